// Round 2
// baseline (1496.482 us; speedup 1.0000x reference)
//
#include <hip/hip_runtime.h>
#include <math.h>

// ---------------- problem constants ----------------
#define POSE_ROWS 144
#define NF 135
#define DD 512
#define KQ 10
#define DCTN 34
#define INN 120
#define OUTN 24
#define VN 87
#define BATCH 256
#define RP 34816              // padded row dim: 256 * 136
#define NODEP 136
#define BN_SCALE 0.9999950000374997f

typedef __attribute__((ext_vector_type(8))) short short8;
typedef __attribute__((ext_vector_type(4))) float floatx4;

static __device__ __forceinline__ ushort f2bf(float f) {
    unsigned u = __builtin_bit_cast(unsigned, f);
    u = (u + 0x7FFFu + ((u >> 16) & 1u)) >> 16;
    return (ushort)u;
}
static __device__ __forceinline__ float bf2f(ushort s) {
    return __builtin_bit_cast(float, (unsigned)s << 16);
}
// fast tanh via exp2
static __device__ __forceinline__ float tanh_fast(float x) {
    float ax = __builtin_fabsf(x);
    float e = __builtin_amdgcn_exp2f(ax * -2.885390081777927f);   // e^{-2ax}
    float t = (1.f - e) * __builtin_amdgcn_rcpf(1.f + e);
    return __builtin_copysignf(t, x);
}

#define GLOAD_LDS(gp, lp) __builtin_amdgcn_global_load_lds( \
    (const __attribute__((address_space(1))) unsigned int*)(const void*)(gp), \
    (__attribute__((address_space(3))) unsigned int*)(void*)(lp), 16, 0, 0)

// ---------------- fused prep kernel (all weight repacks / converts in ONE dispatch) ----
#define PB_POSES 19584
#define PB_K1B   22912
#define PB_K2B   33152
#define PB_WT1   33408
#define PB_WTB   37504
#define PB_WT7   37640
#define PB_A1    37742
#define PB_AB    38147
#define PB_A7    38249
#define PB_BN    39609
#define PB_Z     39610
#define PB_DCT   39615

__global__ __launch_bounds__(256) void prep_all(
    const float* __restrict__ poses, ushort* __restrict__ pb16,
    const float* __restrict__ kw1, const float* __restrict__ qw1,
    ushort* __restrict__ Wt1k, ushort* __restrict__ Wt1q,
    const float* __restrict__ kw2, const float* __restrict__ qw2,
    ushort* __restrict__ Wt2k, ushort* __restrict__ Wt2q,
    const float* __restrict__ gc1_w, ushort* __restrict__ WT1,
    const float* __restrict__ gcb_w, ushort* __restrict__ WTb,
    const float* __restrict__ gc7_w, ushort* __restrict__ WT7,
    const float* __restrict__ gc1_att, ushort* __restrict__ A16_1,
    const float* __restrict__ gcb_att, ushort* __restrict__ A16_B,
    const float* __restrict__ gc7_att, ushort* __restrict__ A16_7,
    const float* __restrict__ bn1_g, const float* __restrict__ bn1_b,
    const float* __restrict__ gcb_g, const float* __restrict__ gcb_beta,
    float* __restrict__ bnT, float* __restrict__ zpadf, float* __restrict__ dct)
{
    const int blk = blockIdx.x;
    const int tid = threadIdx.x;
    if (blk < PB_POSES) {
        int idx = blk * 256 + tid;
        int i = idx % NODEP;
        int row = (idx / NODEP) % POSE_ROWS;
        int b = idx / (NODEP * POSE_ROWS);
        float v = (i < NF) ? poses[((long long)b * POSE_ROWS + row) * NF + i] * 1e-3f : 0.f;
        pb16[idx] = f2bf(v);
    } else if (blk < PB_K1B) {
        int wi = blk - PB_POSES;
        const float* src = (wi < 1664) ? kw1 : qw1;
        ushort* dst = (wi < 1664) ? Wt1k : Wt1q;
        int idx = (wi % 1664) * 256 + tid;
        int n = idx / 832, k = idx % 832;
        int h = k / 136, i = k % 136;
        float v = (i < 135 && h < 6) ? src[((long long)n * 135 + i) * 6 + h] : 0.f;
        dst[idx] = f2bf(v);
    } else if (blk < PB_K2B) {
        int wi = blk - PB_K1B;
        const float* src = (wi < 5120) ? kw2 : qw2;
        ushort* dst = (wi < 5120) ? Wt2k : Wt2q;
        int idx = (wi % 5120) * 256 + tid;
        int n = idx / 2560, k = idx % 2560;
        int h = k / 512, i = k % 512;
        dst[idx] = f2bf(src[((long long)n * 512 + i) * 5 + h]);
    } else if (blk < PB_WT1) {
        int idx = (blk - PB_K2B) * 256 + tid;
        int n = idx / 128, k = idx % 128;
        WT1[idx] = f2bf((k < 68) ? gc1_w[(long long)k * 512 + n] : 0.f);
    } else if (blk < PB_WTB) {
        int g = (blk - PB_WT1) * 256 + tid;
        int L = g >> 18, idx = g & 262143;
        int n = idx / 512, k = idx % 512;
        WTb[g] = f2bf(gcb_w[(long long)L * 262144 + (long long)k * 512 + n]);
    } else if (blk < PB_WT7) {
        int idx = (blk - PB_WTB) * 256 + tid;
        int n = idx / 512, k = idx % 512;
        WT7[idx] = f2bf(gc7_w[(long long)k * 68 + n]);
    } else if (blk < PB_A1) {
        int idx = (blk - PB_WT7) * 256 + tid;
        if (idx < 135 * 192) {
            int r = idx / 192, c = idx % 192;
            A16_1[idx] = f2bf(c < 135 ? gc1_att[r * 135 + c] : 0.f);
        }
    } else if (blk < PB_AB) {
        int idx = (blk - PB_A1) * 256 + tid;
        int r = idx / 192, c = idx % 192;
        A16_B[idx] = f2bf(c < 135 ? gcb_att[r * 135 + c] : 0.f);
    } else if (blk < PB_A7) {
        int idx = (blk - PB_AB) * 256 + tid;
        if (idx < 135 * 192) {
            int r = idx / 192, c = idx % 192;
            A16_7[idx] = f2bf(c < 135 ? gc7_att[r * 135 + c] : 0.f);
        }
    } else if (blk < PB_BN) {
        int g = (blk - PB_A7) * 256 + tid;
        int p = g / 69632, idx = g % 69632;
        int node = idx % 136, m = idx / 136;
        const float* gs = (p == 0) ? bn1_g : (gcb_g + (p - 1) * 69120);
        const float* bs = (p == 0) ? bn1_b : (gcb_beta + (p - 1) * 69120);
        float* gt = bnT + (long long)p * 139264;
        float* bt = gt + 69632;
        gt[idx] = (node < 135) ? gs[node * 512 + m] : 0.f;
        bt[idx] = (node < 135) ? bs[node * 512 + m] : 0.f;
    } else if (blk < PB_Z) {
        if (tid < 128) zpadf[tid] = 0.f;
    } else {
        int idx = (blk - PB_Z) * 256 + tid;
        if (idx < DCTN * DCTN) {
            int k = idx / DCTN, i = idx % DCTN;
            double w = (k == 0) ? sqrt(1.0 / DCTN) : sqrt(2.0 / DCTN);
            dct[idx] = (float)(w * cos(3.14159265358979323846 * (i + 0.5) * k / (double)DCTN));
        }
    }
}

// ---------------- NT MFMA GEMM, BK=64, global_load_lds staging, XOR-swizzled LDS ----------
// (round-0 single-buffer version — used for the big-K conv GEMMs)
// XCD-aware block mapping:
//   mode 0: mb = blockIdx.y, nb = blockIdx.x
//   mode 1: n-partitioned per XCD (stream = B): x=gx&7; s=gx>>3; mb=s%CNT; nb=x*Pc+s/CNT
//   mode 2: m-partitioned per XCD (stream = A): x=gx&7; s=gx>>3; nb=s%CNT; mb=x*Pc+s/CNT
template<int BM, int BN>
__global__ __launch_bounds__(256) void gemm2(
    const ushort* __restrict__ A, const ushort* __restrict__ Bt,
    const ushort* __restrict__ zpad,
    int M, int N, int K,
    int mode, int CNT, int Pc,
    int rpbA, long long sAw, long long sAr, long long sAbz,
    long long sBr, long long sBbz,
    float* __restrict__ C, ushort* __restrict__ C16,
    long long sCbz, long long sCm, long long sCn,
    int do_relu, const float* __restrict__ bias, int bias_mode,
    const float* __restrict__ bnTg, const float* __restrict__ bnTb,
    int do_tanh, const ushort* __restrict__ resid16, const float* __restrict__ resid32)
{
    constexpr int SM = BM / 32, SN = BN / 32;
    constexpr int RA = BM / 32, RB = BN / 32;     // staging rounds, 32 rows each
    __shared__ ushort As[BM * 64];
    __shared__ ushort Bs[BN * 64];

    int mb, nb;
    if (mode == 0) { mb = blockIdx.y; nb = blockIdx.x; }
    else {
        int gx = blockIdx.x;
        int x = gx & 7, s = gx >> 3;
        if (mode == 1) { mb = s % CNT; nb = x * Pc + s / CNT; }
        else           { nb = s % CNT; mb = x * Pc + s / CNT; }
    }
    const int m0 = mb * BM, n0 = nb * BN;
    if (m0 >= M || n0 >= N) return;          // block-uniform: safe before barriers

    const int tid = threadIdx.x;
    const int lane = tid & 63, w = tid >> 6;
    const int bz = blockIdx.z;
    const int wm = (w >> 1) * (BM / 2), wn = (w & 1) * (BN / 2);
    const int chunk = (lane & 7) ^ ((lane >> 3) & 7);

    const ushort* pA[RA]; int stA[RA];
    #pragma unroll
    for (int j = 0; j < RA; j++) {
        int m = m0 + j * 32 + w * 8 + (lane >> 3);
        bool v = m < M;
        long long off = v ? ((long long)(m / rpbA) * sAw + (long long)(m % rpbA) * sAr
                            + (long long)bz * sAbz) : 0;
        pA[j] = v ? (A + off + chunk * 8) : (zpad + chunk * 8);
        stA[j] = v ? 64 : 0;
    }
    const ushort* pB[RB]; int stB[RB];
    #pragma unroll
    for (int j = 0; j < RB; j++) {
        int n = n0 + j * 32 + w * 8 + (lane >> 3);
        bool v = n < N;
        long long off = v ? ((long long)n * sBr + (long long)bz * sBbz) : 0;
        pB[j] = v ? (Bt + off + chunk * 8) : (zpad + chunk * 8);
        stB[j] = v ? 64 : 0;
    }

    floatx4 acc[SM][SN];
    #pragma unroll
    for (int i = 0; i < SM; i++)
        #pragma unroll
        for (int j = 0; j < SN; j++)
            acc[i][j] = (floatx4){0.f, 0.f, 0.f, 0.f};

    for (int k0 = 0; k0 < K; k0 += 64) {
        #pragma unroll
        for (int j = 0; j < RA; j++)
            GLOAD_LDS(pA[j], &As[(j * 32 + w * 8) * 64]);
        #pragma unroll
        for (int j = 0; j < RB; j++)
            GLOAD_LDS(pB[j], &Bs[(j * 32 + w * 8) * 64]);
        __syncthreads();

        #pragma unroll
        for (int kk = 0; kk < 2; kk++) {
            short8 af[SM], bf[SN];
            #pragma unroll
            for (int sm = 0; sm < SM; sm++) {
                int lr = wm + sm * 16 + (lane & 15);
                int slot = ((lane >> 4) + kk * 4) ^ (lr & 7);
                af[sm] = *(const short8*)&As[lr * 64 + slot * 8];
            }
            #pragma unroll
            for (int sn = 0; sn < SN; sn++) {
                int lr = wn + sn * 16 + (lane & 15);
                int slot = ((lane >> 4) + kk * 4) ^ (lr & 7);
                bf[sn] = *(const short8*)&Bs[lr * 64 + slot * 8];
            }
            #pragma unroll
            for (int sm = 0; sm < SM; sm++)
                #pragma unroll
                for (int sn = 0; sn < SN; sn++)
                    acc[sm][sn] = __builtin_amdgcn_mfma_f32_16x16x32_bf16(af[sm], bf[sn], acc[sm][sn], 0, 0, 0);
        }
        __syncthreads();

        #pragma unroll
        for (int j = 0; j < RA; j++) pA[j] += stA[j];
        #pragma unroll
        for (int j = 0; j < RB; j++) pB[j] += stB[j];
    }

    // epilogue: D mapping col(n)=lane&15, row(m)=(lane>>4)*4+r
    const int lc = lane & 15;
    const int lr4 = (lane >> 4) << 2;
    #pragma unroll
    for (int sm = 0; sm < SM; sm++) {
        #pragma unroll
        for (int sn = 0; sn < SN; sn++) {
            int n = n0 + wn + sn * 16 + lc;
            if (n >= N) continue;
            int node = n % 136;
            int mbv = m0 + wm + sm * 16 + lr4;
            float vv[4];
            #pragma unroll
            for (int r = 0; r < 4; r++) {
                int m = mbv + r;
                float v = acc[sm][sn][r];
                if (do_relu) v = fmaxf(v, 0.f);
                if (bias) v += (bias_mode == 1) ? bias[m < M ? m : 0] : bias[n];
                if (bnTg) {
                    long long gi = (long long)(m < M ? m : 0) * 136 + node;
                    v = bnTg[gi] * (v * BN_SCALE) + bnTb[gi];
                }
                if (do_tanh) v = tanh_fast(v);
                long long addr = (long long)bz * sCbz + (long long)m * sCm + (long long)n * sCn;
                if (m < M) {
                    if (resid16) v += bf2f(resid16[addr]);
                    else if (resid32) v += resid32[addr];
                    if (C) C[addr] = v;
                    if (C16 && sCm != 1) C16[addr] = f2bf(v);
                }
                vv[r] = v;
            }
            if (C16 && sCm == 1 && mbv + 3 < M) {
                ushort4 pk;
                pk.x = f2bf(vv[0]); pk.y = f2bf(vv[1]); pk.z = f2bf(vv[2]); pk.w = f2bf(vv[3]);
                *(ushort4*)&C16[(long long)bz * sCbz + mbv + (long long)n * sCn] = pk;
            }
        }
    }
}

// ---------------- full-K-resident 64x64 GEMM (K <= 512) ----------------
// The whole A-panel (64 x K) and B-panel (64 x K) are staged into LDS in ONE
// issue burst (NH k-halves), with a counted-vmcnt pipeline:
//   issue all loads -> s_waitcnt vmcnt(#h1-loads) -> s_barrier -> compute h0
//   -> s_waitcnt vmcnt(0) -> s_barrier -> compute h1
// ONE latency exposure per block instead of K/64; no mid-loop vmcnt(0) drains.
// LDS layout per matrix: [NH][64 rows][HC chunks of 16B], chunk swizzled by
// (row&7) XOR (both sides, involution) -> 2-way-max bank aliasing on ds_read_b128.
template<int KK, int NH>
__global__ __launch_bounds__(256) void gemm_res(
    const ushort* __restrict__ A, const ushort* __restrict__ Bt,
    const ushort* __restrict__ zpad,
    int M, int N,
    int mode, int CNT, int Pc,
    long long sAr, long long sAbz,
    long long sBr, long long sBbz,
    float* __restrict__ C, ushort* __restrict__ C16,
    long long sCbz, long long sCm, long long sCn,
    int do_relu, const float* __restrict__ bias, int bias_mode,
    const float* __restrict__ bnTg, const float* __restrict__ bnTb,
    int do_tanh, const ushort* __restrict__ resid16, const float* __restrict__ resid32)
{
    constexpr int HC = KK / (8 * NH);        // 16B-chunks per row per half
    constexpr int ROUNDS = 64 * HC / 256;    // wave-load rounds per matrix-half
    constexpr int TSTEP = KK / 64 / NH;      // 64-k steps per half
    __shared__ ushort As[NH][64 * HC * 8];
    __shared__ ushort Bs[NH][64 * HC * 8];

    int mb, nb;
    if (mode == 0) { mb = blockIdx.y; nb = blockIdx.x; }
    else {
        int gx = blockIdx.x;
        int x = gx & 7, s = gx >> 3;
        if (mode == 1) { mb = s % CNT; nb = x * Pc + s / CNT; }
        else           { nb = s % CNT; mb = x * Pc + s / CNT; }
    }
    const int m0 = mb * 64, n0 = nb * 64;
    if (m0 >= M || n0 >= N) return;          // block-uniform

    const int tid = threadIdx.x;
    const int lane = tid & 63, w = tid >> 6;
    const int bz = blockIdx.z;
    const int wm = (w >> 1) * 32, wn = (w & 1) * 32;

    // ---- issue ALL staging loads; order pinned per-half by sched_barrier ----
    #pragma unroll
    for (int h = 0; h < NH; h++) {
        #pragma unroll
        for (int r = 0; r < ROUNDS; r++) {
            int u = r * 256 + w * 64 + lane;
            int row = u / HC, cin = u % HC;
            int m = m0 + row;
            const ushort* src = (m < M)
                ? (A + (long long)m * sAr + (long long)bz * sAbz
                     + (h * HC + (cin ^ (row & 7))) * 8)
                : zpad;
            GLOAD_LDS(src, &As[h][(r * 256 + w * 64) * 8]);
        }
        #pragma unroll
        for (int r = 0; r < ROUNDS; r++) {
            int u = r * 256 + w * 64 + lane;
            int row = u / HC, cin = u % HC;
            int n = n0 + row;
            const ushort* src = (n < N)
                ? (Bt + (long long)n * sBr + (long long)bz * sBbz
                      + (h * HC + (cin ^ (row & 7))) * 8)
                : zpad;
            GLOAD_LDS(src, &Bs[h][(r * 256 + w * 64) * 8]);
        }
        __builtin_amdgcn_sched_barrier(0);   // keep h0 loads older than h1 loads
    }

    floatx4 acc[2][2];
    #pragma unroll
    for (int i = 0; i < 2; i++)
        #pragma unroll
        for (int j = 0; j < 2; j++)
            acc[i][j] = (floatx4){0.f, 0.f, 0.f, 0.f};

    #pragma unroll
    for (int h = 0; h < NH; h++) {
        if (h == 0) {
            // wait for h0's own loads only (NH-1 halves still in flight)
            asm volatile("s_waitcnt vmcnt(%0)" :: "n"(2 * ROUNDS * (NH - 1)) : "memory");
        } else {
            asm volatile("s_waitcnt vmcnt(0)" ::: "memory");
        }
        __builtin_amdgcn_sched_barrier(0);
        __builtin_amdgcn_s_barrier();        // all waves' half-h loads resident
        #pragma unroll
        for (int t = 0; t < TSTEP; t++) {
            #pragma unroll
            for (int kk = 0; kk < 2; kk++) {
                int c4 = t * 8 + kk * 4 + (lane >> 4);   // chunk within half
                short8 af[2], bf[2];
                #pragma unroll
                for (int sm = 0; sm < 2; sm++) {
                    int lr = wm + sm * 16 + (lane & 15);
                    af[sm] = *(const short8*)&As[h][(lr * HC + (c4 ^ (lr & 7))) * 8];
                }
                #pragma unroll
                for (int sn = 0; sn < 2; sn++) {
                    int lr = wn + sn * 16 + (lane & 15);
                    bf[sn] = *(const short8*)&Bs[h][(lr * HC + (c4 ^ (lr & 7))) * 8];
                }
                #pragma unroll
                for (int sm = 0; sm < 2; sm++)
                    #pragma unroll
                    for (int sn = 0; sn < 2; sn++)
                        acc[sm][sn] = __builtin_amdgcn_mfma_f32_16x16x32_bf16(af[sm], bf[sn], acc[sm][sn], 0, 0, 0);
            }
        }
    }

    // epilogue: D mapping col(n)=lane&15, row(m)=(lane>>4)*4+r
    const int lc = lane & 15;
    const int lr4 = (lane >> 4) << 2;
    #pragma unroll
    for (int sm = 0; sm < 2; sm++) {
        #pragma unroll
        for (int sn = 0; sn < 2; sn++) {
            int n = n0 + wn + sn * 16 + lc;
            if (n >= N) continue;
            int node = n % 136;
            int mbv = m0 + wm + sm * 16 + lr4;
            float vv[4];
            #pragma unroll
            for (int r = 0; r < 4; r++) {
                int m = mbv + r;
                float v = acc[sm][sn][r];
                if (do_relu) v = fmaxf(v, 0.f);
                if (bias) v += (bias_mode == 1) ? bias[m < M ? m : 0] : bias[n];
                if (bnTg) {
                    long long gi = (long long)(m < M ? m : 0) * 136 + node;
                    v = bnTg[gi] * (v * BN_SCALE) + bnTb[gi];
                }
                if (do_tanh) v = tanh_fast(v);
                long long addr = (long long)bz * sCbz + (long long)m * sCm + (long long)n * sCn;
                if (m < M) {
                    if (resid16) v += bf2f(resid16[addr]);
                    else if (resid32) v += resid32[addr];
                    if (C) C[addr] = v;
                    if (C16 && sCm != 1) C16[addr] = f2bf(v);
                }
                vv[r] = v;
            }
            if (C16 && sCm == 1 && mbv + 3 < M) {
                ushort4 pk;
                pk.x = f2bf(vv[0]); pk.y = f2bf(vv[1]); pk.z = f2bf(vv[2]); pk.w = f2bf(vv[3]);
                *(ushort4*)&C16[(long long)bz * sCbz + mbv + (long long)n * sCn] = pk;
            }
        }
    }
}

// ---------------- attention scores + normalize (wave-parallel) ----------------
__global__ __launch_bounds__(256) void att_k(const float* __restrict__ kf, const float* __restrict__ qf,
                                             float* __restrict__ att) {
    int b = blockIdx.x;
    int tid = threadIdx.x;
    int lane = tid & 63, w = tid >> 6;
    __shared__ float s[96];
    __shared__ float ssum;
    const float* qb = qf + b * DD + lane * 8;
    float4 q0 = *(const float4*)qb;
    float4 q1 = *(const float4*)(qb + 4);
    const float* kb = kf + (long long)b * VN * DD;
    for (int v = w; v < VN; v += 4) {
        const float* kr = kb + v * DD + lane * 8;
        float4 k0 = *(const float4*)kr;
        float4 k1 = *(const float4*)(kr + 4);
        float p = q0.x * k0.x + q0.y * k0.y + q0.z * k0.z + q0.w * k0.w
                + q1.x * k1.x + q1.y * k1.y + q1.z * k1.z + q1.w * k1.w;
        #pragma unroll
        for (int off = 32; off; off >>= 1) p += __shfl_xor(p, off);
        if (lane == 0) s[v] = p + 1e-15f;
    }
    __syncthreads();
    if (tid < 64) {
        float p2 = (tid < VN ? s[tid] : 0.f) + ((tid + 64) < VN ? s[tid + 64] : 0.f);
        #pragma unroll
        for (int off = 32; off; off >>= 1) p2 += __shfl_xor(p2, off);
        if (tid == 0) ssum = p2;
    }
    __syncthreads();
    float inv = 1.f / ssum;
    for (int v = tid; v < VN; v += 256) att[b * VN + v] = s[v] * inv;
}

// ---------------- w34[b,t,f] = sum_v att[b,v] * poses[b,v+t,f] ----------------
__global__ void weighted_k(const float* __restrict__ poses, const float* __restrict__ att,
                           float* __restrict__ w34) {
    int t = blockIdx.x;
    int b = blockIdx.y;
    int f = threadIdx.x;
    if (f >= NF) return;
    const float* pb = poses + (long long)b * POSE_ROWS * NF + t * NF + f;
    const float* ab = att + b * VN;
    float acc = 0.f;
    for (int v = 0; v < VN; v++) acc += ab[v] * pb[v * NF];
    w34[(long long)b * DCTN * NF + t * NF + f] = acc;
}

// ---------------- x = concat(dct_in, dct_att); node-major f32 + feature-major bf16 ----
__global__ void build_x(const float* __restrict__ poses, const float* __restrict__ w34,
                        const float* __restrict__ dctm, float* __restrict__ x32,
                        ushort* __restrict__ xT16) {
    int idx = blockIdx.x * 256 + threadIdx.x;
    if (idx >= BATCH * NF * 68) return;
    int kk = idx % 68;
    int f = (idx / 68) % NF;
    int b = idx / (68 * NF);
    float acc = 0.f;
    if (kk < DCTN) {
        const float* pb = poses + (long long)b * POSE_ROWS * NF;
        #pragma unroll
        for (int t = 0; t < DCTN; t++) {
            int row = (t < KQ) ? (INN - KQ + t) : (INN - 1);
            acc += dctm[kk * DCTN + t] * pb[row * NF + f];
        }
    } else {
        int k2 = kk - DCTN;
        const float* wb = w34 + (long long)b * DCTN * NF + f;
        #pragma unroll
        for (int t = 0; t < DCTN; t++) acc += dctm[k2 * DCTN + t] * wb[t * NF];
    }
    long long R = (long long)b * NODEP + f;
    x32[R * 68 + kk] = acc;
    xT16[(long long)kk * RP + R] = f2bf(acc);
}

// ---------------- preds[b,t,f] = sum_k dct[k][10+t] * h32[(b*136+f)*68+k] ----------------
__global__ void idct_out(const float* __restrict__ h32, const float* __restrict__ dctm,
                         float* __restrict__ out) {
    int idx = blockIdx.x * 256 + threadIdx.x;
    if (idx >= BATCH * OUTN * NF) return;
    int f = idx % NF;
    int t = (idx / NF) % OUTN;
    int b = idx / (NF * OUTN);
    const float* yr = h32 + ((long long)b * NODEP + f) * 68;
    float acc = 0.f;
    #pragma unroll
    for (int k = 0; k < DCTN; k++) acc += dctm[k * DCTN + (KQ + t)] * yr[k];
    out[idx] = acc;
}

// ---------------- host ----------------
extern "C" void kernel_launch(void* const* d_in, const int* in_sizes, int n_in,
                              void* d_out, int out_size, void* d_ws, size_t ws_size,
                              hipStream_t stream) {
    const float* poses   = (const float*)d_in[0];
    const float* qw1     = (const float*)d_in[1];
    const float* qw2     = (const float*)d_in[2];
    const float* kw1     = (const float*)d_in[3];
    const float* kw2     = (const float*)d_in[4];
    const float* gc1_att = (const float*)d_in[5];
    const float* gc1_w   = (const float*)d_in[6];
    const float* gc1_b   = (const float*)d_in[7];
    const float* bn1_g   = (const float*)d_in[8];
    const float* bn1_b   = (const float*)d_in[9];
    const float* gcb_att = (const float*)d_in[10];
    const float* gcb_w   = (const float*)d_in[11];
    const float* gcb_b   = (const float*)d_in[12];
    const float* gcb_g   = (const float*)d_in[13];
    const float* gcb_beta= (const float*)d_in[14];
    const float* gc7_att = (const float*)d_in[15];
    const float* gc7_w   = (const float*)d_in[16];
    const float* gc7_b   = (const float*)d_in[17];
    float* out = (float*)d_out;
    float* w = (float*)d_ws;

    // ---- workspace layout (f32 units) ----
    float* dct   = w;                      // 1156 -> pad 1280
    float* att   = w + 1280;               // -> 23808
    float* w34   = w + 23808;              // -> 1198848
    float* x32   = w + 1198848;            // RP*68 -> 3566336
    float* h32   = w + 3566336;            // RP*68 -> 5933824
    float* qf    = w + 5933824;            // -> 6064896
    ushort* su   = (ushort*)(w + 6064896); // bf16 weight region
    ushort* WT1    = su;                   // 512*128   = 65536
    ushort* WTb    = su + 65536;           // 4*512*512 = 1048576
    ushort* WT7    = su + 1114112;         // 68*512    = 34816
    ushort* A16_1  = su + 1148928;         // 135*192   = 25920
    ushort* A16_B  = su + 1174848;         // 540*192   = 103680
    ushort* A16_7  = su + 1278528;         // 25920
    float* bnT   = w + 6717120;            // 10 * 69632 -> 7413440
    float* kf    = w + 7413440;            // 256*87*512 -> 18816704
    ushort* R2   = (ushort*)(w + 18816704);
    ushort* yT16  = R2;
    ushort* r1k16 = R2;                    // phase-A alias
    ushort* r1q16 = R2 + 11927552;
    ushort* R3   = (ushort*)(w + 27729600);
    ushort* hT16  = R3;
    ushort* pb16  = R3;                    // phase-A alias
    ushort* Wt1k  = R3 + 5013504;
    ushort* Wt1q  = R3 + 5439488;
    ushort* Wt2k  = R3 + 5865472;
    ushort* Wt2q  = R3 + 7176192;
    ushort* R4   = (ushort*)(w + 36642496);
    ushort* zN16  = R4;
    ushort* xT16  = R4;                    // alias (dead before zN16 written)
    ushort* z116  = R4 + 2367488;          // RP*80
    float* zpadf = w + 45555392;           // 128 f zero page
    const ushort* zpad = (const ushort*)zpadf;

    const int INF_RPB = 1 << 30;

    // ---- fused prep (one dispatch) ----
    prep_all<<<PB_DCT, 256, 0, stream>>>(
        poses, pb16, kw1, qw1, Wt1k, Wt1q, kw2, qw2, Wt2k, Wt2q,
        gc1_w, WT1, gcb_w, WTb, gc7_w, WT7,
        gc1_att, A16_1, gcb_att, A16_B, gc7_att, A16_7,
        bn1_g, bn1_b, gcb_g, gcb_beta, bnT, zpadf, dct);

    // ---- conv stack (big-K: stays on gemm2) ----
    // conv1k: BM=128,BN=64; A-stream m-partitioned per XCD (mode 2): 182 m-blocks, Pc=23
    gemm2<128,64><<<dim3(1472, 1, 1), 256, 0, stream>>>(pb16, Wt1k, zpad, 23296, 512, 832,
        2, 8, 23, 91, 19584LL, 136LL, 0LL, 832LL, 0LL,
        (float*)nullptr, r1k16, 0LL, 512LL, 1LL, 1, nullptr, 0, nullptr, nullptr, 0, nullptr, nullptr);
    gemm2<128,128><<<dim3(4, 10, 1), 256, 0, stream>>>(pb16 + 110*136, Wt1q, zpad, 1280, 512, 832,
        0, 0, 0, 5, 19584LL, 136LL, 0LL, 832LL, 0LL,
        (float*)nullptr, r1q16, 0LL, 512LL, 1LL, 1, nullptr, 0, nullptr, nullptr, 0, nullptr, nullptr);
    // conv2k: BM=128,BN=64; mode 2: 174 m-blocks, Pc=22
    gemm2<128,64><<<dim3(1408, 1, 1), 256, 0, stream>>>(r1k16, Wt2k, zpad, 22272, 512, 2560,
        2, 8, 22, 87, 46592LL, 512LL, 0LL, 2560LL, 0LL,
        kf, (ushort*)nullptr, 0LL, 512LL, 1LL, 1, nullptr, 0, nullptr, nullptr, 0, nullptr, nullptr);
    gemm2<64,64><<<dim3(8, 4, 1), 256, 0, stream>>>(r1q16, Wt2q, zpad, 256, 512, 2560,
        0, 0, 0, INF_RPB, 0LL, 2560LL, 0LL, 2560LL, 0LL,
        qf, (ushort*)nullptr, 0LL, 512LL, 1LL, 1, nullptr, 0, nullptr, nullptr, 0, nullptr, nullptr);

    // ---- attention + x ----
    att_k<<<BATCH, 256, 0, stream>>>(kf, qf, att);
    weighted_k<<<dim3(DCTN, BATCH), 192, 0, stream>>>(poses, att, w34);
    build_x<<<(BATCH * NF * 68 + 255) / 256, 256, 0, stream>>>(poses, w34, dct, x32, xT16);

    // ---- gc1: mix then W(68->512) ----  (full-K-resident kernels)
    gemm_res<192,1><<<dim3(3, 2, BATCH), 256, 0, stream>>>(xT16, A16_1, zpad, 68, 135,
        0, 0, 0, (long long)RP, 136LL, 192LL, 0LL,
        (float*)nullptr, z116, 10880LL, 1LL, 80LL, 0, nullptr, 0, nullptr, nullptr, 0, nullptr, nullptr);
    // gc1 W: K=128 resident; mode 1: 8 m-blocks, Pc=68, grid 8*544
    gemm_res<128,1><<<dim3(4352, 1, 1), 256, 0, stream>>>(WT1, z116, zpad, 512, RP,
        1, 8, 68, 128LL, 0LL, 80LL, 0LL,
        (float*)nullptr, yT16, 0LL, (long long)RP, 1LL, 0, gc1_b, 1, bnT, bnT + 69632, 1, nullptr, nullptr);

    // ---- residual GCN blocks ----
    for (int L = 0; L < 4; L++) {
        const ushort* min = (L & 1) ? hT16 : yT16;
        gemm_res<192,1><<<dim3(3, 8, BATCH), 256, 0, stream>>>(min, A16_B + L*25920, zpad, 512, 135,
            0, 0, 0, (long long)RP, 136LL, 192LL, 0LL,
            (float*)nullptr, zN16, 69632LL, 1LL, 512LL, 0, nullptr, 0, nullptr, nullptr, 0, nullptr, nullptr);
        // W: K=512 resident, 2-half counted-vmcnt pipeline; mode 1: 8 m-blocks, Pc=68
        gemm_res<512,2><<<dim3(4352, 1, 1), 256, 0, stream>>>(WTb + L*262144, zN16, zpad, 512, RP,
            1, 8, 68, 512LL, 0LL, 512LL, 0LL,
            (float*)nullptr, (L & 1) ? yT16 : hT16, 0LL, (long long)RP, 1LL,
            0, gcb_b + L*512, 1, bnT + (1 + L) * 139264, bnT + (1 + L) * 139264 + 69632, 1,
            (L & 1) ? yT16 : (const ushort*)nullptr, nullptr);
    }

    // ---- gc7: mix then W(512->68) + bias + x residual ----
    gemm_res<192,1><<<dim3(3, 8, BATCH), 256, 0, stream>>>(yT16, A16_7, zpad, 512, 135,
        0, 0, 0, (long long)RP, 136LL, 192LL, 0LL,
        (float*)nullptr, zN16, 69632LL, 1LL, 512LL, 0, nullptr, 0, nullptr, nullptr, 0, nullptr, nullptr);
    // gc7 W: K=512 resident; A-stream m-partitioned (mode 2): CNT=2 n-blocks, Pc=68
    gemm_res<512,2><<<dim3(1088, 1, 1), 256, 0, stream>>>(zN16, WT7, zpad, RP, 68,
        2, 2, 68, 512LL, 0LL, 512LL, 0LL,
        h32, (ushort*)nullptr, 0LL, 68LL, 1LL, 0, gc7_b, 2, nullptr, nullptr, 0, nullptr, x32);

    idct_out<<<(BATCH * OUTN * NF + 255) / 256, 256, 0, stream>>>(h32, dct, out);
}

// Round 3
// 1084.194 us; speedup vs baseline: 1.3803x; 1.3803x over previous
//
#include <hip/hip_runtime.h>
#include <math.h>

// ---------------- problem constants ----------------
#define POSE_ROWS 144
#define NF 135
#define DD 512
#define KQ 10
#define DCTN 34
#define INN 120
#define OUTN 24
#define VN 87
#define BATCH 256
#define RP 34816              // padded row dim: 256 * 136
#define NODEP 136
#define BN_SCALE 0.9999950000374997f

typedef __attribute__((ext_vector_type(8))) short short8;
typedef __attribute__((ext_vector_type(4))) float floatx4;

static __device__ __forceinline__ ushort f2bf(float f) {
    unsigned u = __builtin_bit_cast(unsigned, f);
    u = (u + 0x7FFFu + ((u >> 16) & 1u)) >> 16;
    return (ushort)u;
}
static __device__ __forceinline__ float bf2f(ushort s) {
    return __builtin_bit_cast(float, (unsigned)s << 16);
}
// fast tanh via exp2
static __device__ __forceinline__ float tanh_fast(float x) {
    float ax = __builtin_fabsf(x);
    float e = __builtin_amdgcn_exp2f(ax * -2.885390081777927f);   // e^{-2ax}
    float t = (1.f - e) * __builtin_amdgcn_rcpf(1.f + e);
    return __builtin_copysignf(t, x);
}

#define GLOAD_LDS(gp, lp) __builtin_amdgcn_global_load_lds( \
    (const __attribute__((address_space(1))) unsigned int*)(const void*)(gp), \
    (__attribute__((address_space(3))) unsigned int*)(void*)(lp), 16, 0, 0)

// ---------------- fused prep kernel (all weight repacks / converts in ONE dispatch) ----
#define PB_POSES 19584
#define PB_K1B   22912
#define PB_K2B   33152
#define PB_WT1   33408
#define PB_WTB   37504
#define PB_WT7   37640
#define PB_A1    37742
#define PB_AB    38147
#define PB_A7    38249
#define PB_BN    39609
#define PB_Z     39610
#define PB_DCT   39615

__global__ __launch_bounds__(256) void prep_all(
    const float* __restrict__ poses, ushort* __restrict__ pb16,
    const float* __restrict__ kw1, const float* __restrict__ qw1,
    ushort* __restrict__ Wt1k, ushort* __restrict__ Wt1q,
    const float* __restrict__ kw2, const float* __restrict__ qw2,
    ushort* __restrict__ Wt2k, ushort* __restrict__ Wt2q,
    const float* __restrict__ gc1_w, ushort* __restrict__ WT1,
    const float* __restrict__ gcb_w, ushort* __restrict__ WTb,
    const float* __restrict__ gc7_w, ushort* __restrict__ WT7,
    const float* __restrict__ gc1_att, ushort* __restrict__ A16_1,
    const float* __restrict__ gcb_att, ushort* __restrict__ A16_B,
    const float* __restrict__ gc7_att, ushort* __restrict__ A16_7,
    const float* __restrict__ bn1_g, const float* __restrict__ bn1_b,
    const float* __restrict__ gcb_g, const float* __restrict__ gcb_beta,
    float* __restrict__ bnT, float* __restrict__ zpadf, float* __restrict__ dct)
{
    const int blk = blockIdx.x;
    const int tid = threadIdx.x;
    if (blk < PB_POSES) {
        int idx = blk * 256 + tid;
        int i = idx % NODEP;
        int row = (idx / NODEP) % POSE_ROWS;
        int b = idx / (NODEP * POSE_ROWS);
        float v = (i < NF) ? poses[((long long)b * POSE_ROWS + row) * NF + i] * 1e-3f : 0.f;
        pb16[idx] = f2bf(v);
    } else if (blk < PB_K1B) {
        int wi = blk - PB_POSES;
        const float* src = (wi < 1664) ? kw1 : qw1;
        ushort* dst = (wi < 1664) ? Wt1k : Wt1q;
        int idx = (wi % 1664) * 256 + tid;
        int n = idx / 832, k = idx % 832;
        int h = k / 136, i = k % 136;
        float v = (i < 135 && h < 6) ? src[((long long)n * 135 + i) * 6 + h] : 0.f;
        dst[idx] = f2bf(v);
    } else if (blk < PB_K2B) {
        int wi = blk - PB_K1B;
        const float* src = (wi < 5120) ? kw2 : qw2;
        ushort* dst = (wi < 5120) ? Wt2k : Wt2q;
        int idx = (wi % 5120) * 256 + tid;
        int n = idx / 2560, k = idx % 2560;
        int h = k / 512, i = k % 512;
        dst[idx] = f2bf(src[((long long)n * 512 + i) * 5 + h]);
    } else if (blk < PB_WT1) {
        int idx = (blk - PB_K2B) * 256 + tid;
        int n = idx / 128, k = idx % 128;
        WT1[idx] = f2bf((k < 68) ? gc1_w[(long long)k * 512 + n] : 0.f);
    } else if (blk < PB_WTB) {
        int g = (blk - PB_WT1) * 256 + tid;
        int L = g >> 18, idx = g & 262143;
        int n = idx / 512, k = idx % 512;
        WTb[g] = f2bf(gcb_w[(long long)L * 262144 + (long long)k * 512 + n]);
    } else if (blk < PB_WT7) {
        int idx = (blk - PB_WTB) * 256 + tid;
        int n = idx / 512, k = idx % 512;
        WT7[idx] = f2bf(gc7_w[(long long)k * 68 + n]);
    } else if (blk < PB_A1) {
        int idx = (blk - PB_WT7) * 256 + tid;
        if (idx < 135 * 192) {
            int r = idx / 192, c = idx % 192;
            A16_1[idx] = f2bf(c < 135 ? gc1_att[r * 135 + c] : 0.f);
        }
    } else if (blk < PB_AB) {
        int idx = (blk - PB_A1) * 256 + tid;
        int r = idx / 192, c = idx % 192;
        A16_B[idx] = f2bf(c < 135 ? gcb_att[r * 135 + c] : 0.f);
    } else if (blk < PB_A7) {
        int idx = (blk - PB_AB) * 256 + tid;
        if (idx < 135 * 192) {
            int r = idx / 192, c = idx % 192;
            A16_7[idx] = f2bf(c < 135 ? gc7_att[r * 135 + c] : 0.f);
        }
    } else if (blk < PB_BN) {
        int g = (blk - PB_A7) * 256 + tid;
        int p = g / 69632, idx = g % 69632;
        int node = idx % 136, m = idx / 136;
        const float* gs = (p == 0) ? bn1_g : (gcb_g + (p - 1) * 69120);
        const float* bs = (p == 0) ? bn1_b : (gcb_beta + (p - 1) * 69120);
        float* gt = bnT + (long long)p * 139264;
        float* bt = gt + 69632;
        gt[idx] = (node < 135) ? gs[node * 512 + m] : 0.f;
        bt[idx] = (node < 135) ? bs[node * 512 + m] : 0.f;
    } else if (blk < PB_Z) {
        if (tid < 128) zpadf[tid] = 0.f;
    } else {
        int idx = (blk - PB_Z) * 256 + tid;
        if (idx < DCTN * DCTN) {
            int k = idx / DCTN, i = idx % DCTN;
            double w = (k == 0) ? sqrt(1.0 / DCTN) : sqrt(2.0 / DCTN);
            dct[idx] = (float)(w * cos(3.14159265358979323846 * (i + 0.5) * k / (double)DCTN));
        }
    }
}

// ---------------- NT MFMA GEMM, BK=64, global_load_lds staging, XOR-swizzled LDS ----------
// XCD-aware block mapping:
//   mode 0: mb = blockIdx.y, nb = blockIdx.x
//   mode 1: n-partitioned per XCD (stream = B): x=gx&7; s=gx>>3; mb=s%CNT; nb=x*Pc+s/CNT
//   mode 2: m-partitioned per XCD (stream = A): x=gx&7; s=gx>>3; nb=s%CNT; mb=x*Pc+s/CNT
template<int BM, int BN>
__global__ __launch_bounds__(256) void gemm2(
    const ushort* __restrict__ A, const ushort* __restrict__ Bt,
    const ushort* __restrict__ zpad,
    int M, int N, int K,
    int mode, int CNT, int Pc,
    int rpbA, long long sAw, long long sAr, long long sAbz,
    long long sBr, long long sBbz,
    float* __restrict__ C, ushort* __restrict__ C16,
    long long sCbz, long long sCm, long long sCn,
    int do_relu, const float* __restrict__ bias, int bias_mode,
    const float* __restrict__ bnTg, const float* __restrict__ bnTb,
    int do_tanh, const ushort* __restrict__ resid16, const float* __restrict__ resid32)
{
    constexpr int SM = BM / 32, SN = BN / 32;
    constexpr int RA = BM / 32, RB = BN / 32;     // staging rounds, 32 rows each
    __shared__ ushort As[BM * 64];
    __shared__ ushort Bs[BN * 64];

    int mb, nb;
    if (mode == 0) { mb = blockIdx.y; nb = blockIdx.x; }
    else {
        int gx = blockIdx.x;
        int x = gx & 7, s = gx >> 3;
        if (mode == 1) { mb = s % CNT; nb = x * Pc + s / CNT; }
        else           { nb = s % CNT; mb = x * Pc + s / CNT; }
    }
    const int m0 = mb * BM, n0 = nb * BN;
    if (m0 >= M || n0 >= N) return;          // block-uniform: safe before barriers

    const int tid = threadIdx.x;
    const int lane = tid & 63, w = tid >> 6;
    const int bz = blockIdx.z;
    const int wm = (w >> 1) * (BM / 2), wn = (w & 1) * (BN / 2);
    const int chunk = (lane & 7) ^ ((lane >> 3) & 7);

    const ushort* pA[RA]; int stA[RA];
    #pragma unroll
    for (int j = 0; j < RA; j++) {
        int m = m0 + j * 32 + w * 8 + (lane >> 3);
        bool v = m < M;
        long long off = v ? ((long long)(m / rpbA) * sAw + (long long)(m % rpbA) * sAr
                            + (long long)bz * sAbz) : 0;
        pA[j] = v ? (A + off + chunk * 8) : (zpad + chunk * 8);
        stA[j] = v ? 64 : 0;
    }
    const ushort* pB[RB]; int stB[RB];
    #pragma unroll
    for (int j = 0; j < RB; j++) {
        int n = n0 + j * 32 + w * 8 + (lane >> 3);
        bool v = n < N;
        long long off = v ? ((long long)n * sBr + (long long)bz * sBbz) : 0;
        pB[j] = v ? (Bt + off + chunk * 8) : (zpad + chunk * 8);
        stB[j] = v ? 64 : 0;
    }

    floatx4 acc[SM][SN];
    #pragma unroll
    for (int i = 0; i < SM; i++)
        #pragma unroll
        for (int j = 0; j < SN; j++)
            acc[i][j] = (floatx4){0.f, 0.f, 0.f, 0.f};

    for (int k0 = 0; k0 < K; k0 += 64) {
        #pragma unroll
        for (int j = 0; j < RA; j++)
            GLOAD_LDS(pA[j], &As[(j * 32 + w * 8) * 64]);
        #pragma unroll
        for (int j = 0; j < RB; j++)
            GLOAD_LDS(pB[j], &Bs[(j * 32 + w * 8) * 64]);
        __syncthreads();

        #pragma unroll
        for (int kk = 0; kk < 2; kk++) {
            short8 af[SM], bf[SN];
            #pragma unroll
            for (int sm = 0; sm < SM; sm++) {
                int lr = wm + sm * 16 + (lane & 15);
                int slot = ((lane >> 4) + kk * 4) ^ (lr & 7);
                af[sm] = *(const short8*)&As[lr * 64 + slot * 8];
            }
            #pragma unroll
            for (int sn = 0; sn < SN; sn++) {
                int lr = wn + sn * 16 + (lane & 15);
                int slot = ((lane >> 4) + kk * 4) ^ (lr & 7);
                bf[sn] = *(const short8*)&Bs[lr * 64 + slot * 8];
            }
            #pragma unroll
            for (int sm = 0; sm < SM; sm++)
                #pragma unroll
                for (int sn = 0; sn < SN; sn++)
                    acc[sm][sn] = __builtin_amdgcn_mfma_f32_16x16x32_bf16(af[sm], bf[sn], acc[sm][sn], 0, 0, 0);
        }
        __syncthreads();

        #pragma unroll
        for (int j = 0; j < RA; j++) pA[j] += stA[j];
        #pragma unroll
        for (int j = 0; j < RB; j++) pB[j] += stB[j];
    }

    // epilogue: D mapping col(n)=lane&15, row(m)=(lane>>4)*4+r
    const int lc = lane & 15;
    const int lr4 = (lane >> 4) << 2;
    #pragma unroll
    for (int sm = 0; sm < SM; sm++) {
        #pragma unroll
        for (int sn = 0; sn < SN; sn++) {
            int n = n0 + wn + sn * 16 + lc;
            if (n >= N) continue;
            int node = n % 136;
            int mbv = m0 + wm + sm * 16 + lr4;
            float vv[4];
            #pragma unroll
            for (int r = 0; r < 4; r++) {
                int m = mbv + r;
                float v = acc[sm][sn][r];
                if (do_relu) v = fmaxf(v, 0.f);
                if (bias) v += (bias_mode == 1) ? bias[m < M ? m : 0] : bias[n];
                if (bnTg) {
                    long long gi = (long long)(m < M ? m : 0) * 136 + node;
                    v = bnTg[gi] * (v * BN_SCALE) + bnTb[gi];
                }
                if (do_tanh) v = tanh_fast(v);
                long long addr = (long long)bz * sCbz + (long long)m * sCm + (long long)n * sCn;
                if (m < M) {
                    if (resid16) v += bf2f(resid16[addr]);
                    else if (resid32) v += resid32[addr];
                    if (C) C[addr] = v;
                    if (C16 && sCm != 1) C16[addr] = f2bf(v);
                }
                vv[r] = v;
            }
            if (C16 && sCm == 1 && mbv + 3 < M) {
                ushort4 pk;
                pk.x = f2bf(vv[0]); pk.y = f2bf(vv[1]); pk.z = f2bf(vv[2]); pk.w = f2bf(vv[3]);
                *(ushort4*)&C16[(long long)bz * sCbz + mbv + (long long)n * sCn] = pk;
            }
        }
    }
}

// ---------------- attention scores + normalize (wave-parallel) ----------------
__global__ __launch_bounds__(256) void att_k(const float* __restrict__ kf, const float* __restrict__ qf,
                                             float* __restrict__ att) {
    int b = blockIdx.x;
    int tid = threadIdx.x;
    int lane = tid & 63, w = tid >> 6;
    __shared__ float s[96];
    __shared__ float ssum;
    const float* qb = qf + b * DD + lane * 8;
    float4 q0 = *(const float4*)qb;
    float4 q1 = *(const float4*)(qb + 4);
    const float* kb = kf + (long long)b * VN * DD;
    for (int v = w; v < VN; v += 4) {
        const float* kr = kb + v * DD + lane * 8;
        float4 k0 = *(const float4*)kr;
        float4 k1 = *(const float4*)(kr + 4);
        float p = q0.x * k0.x + q0.y * k0.y + q0.z * k0.z + q0.w * k0.w
                + q1.x * k1.x + q1.y * k1.y + q1.z * k1.z + q1.w * k1.w;
        #pragma unroll
        for (int off = 32; off; off >>= 1) p += __shfl_xor(p, off);
        if (lane == 0) s[v] = p + 1e-15f;
    }
    __syncthreads();
    if (tid < 64) {
        float p2 = (tid < VN ? s[tid] : 0.f) + ((tid + 64) < VN ? s[tid + 64] : 0.f);
        #pragma unroll
        for (int off = 32; off; off >>= 1) p2 += __shfl_xor(p2, off);
        if (tid == 0) ssum = p2;
    }
    __syncthreads();
    float inv = 1.f / ssum;
    for (int v = tid; v < VN; v += 256) att[b * VN + v] = s[v] * inv;
}

// ---------------- w34[b,t,f] = sum_v att[b,v] * poses[b,v+t,f] ----------------
__global__ void weighted_k(const float* __restrict__ poses, const float* __restrict__ att,
                           float* __restrict__ w34) {
    int t = blockIdx.x;
    int b = blockIdx.y;
    int f = threadIdx.x;
    if (f >= NF) return;
    const float* pb = poses + (long long)b * POSE_ROWS * NF + t * NF + f;
    const float* ab = att + b * VN;
    float acc = 0.f;
    for (int v = 0; v < VN; v++) acc += ab[v] * pb[v * NF];
    w34[(long long)b * DCTN * NF + t * NF + f] = acc;
}

// ---------------- x = concat(dct_in, dct_att); node-major f32 + feature-major bf16 ----
__global__ void build_x(const float* __restrict__ poses, const float* __restrict__ w34,
                        const float* __restrict__ dctm, float* __restrict__ x32,
                        ushort* __restrict__ xT16) {
    int idx = blockIdx.x * 256 + threadIdx.x;
    if (idx >= BATCH * NF * 68) return;
    int kk = idx % 68;
    int f = (idx / 68) % NF;
    int b = idx / (68 * NF);
    float acc = 0.f;
    if (kk < DCTN) {
        const float* pb = poses + (long long)b * POSE_ROWS * NF;
        #pragma unroll
        for (int t = 0; t < DCTN; t++) {
            int row = (t < KQ) ? (INN - KQ + t) : (INN - 1);
            acc += dctm[kk * DCTN + t] * pb[row * NF + f];
        }
    } else {
        int k2 = kk - DCTN;
        const float* wb = w34 + (long long)b * DCTN * NF + f;
        #pragma unroll
        for (int t = 0; t < DCTN; t++) acc += dctm[k2 * DCTN + t] * wb[t * NF];
    }
    long long R = (long long)b * NODEP + f;
    x32[R * 68 + kk] = acc;
    xT16[(long long)kk * RP + R] = f2bf(acc);
}

// ---------------- preds[b,t,f] = sum_k dct[k][10+t] * h32[(b*136+f)*68+k] ----------------
__global__ void idct_out(const float* __restrict__ h32, const float* __restrict__ dctm,
                         float* __restrict__ out) {
    int idx = blockIdx.x * 256 + threadIdx.x;
    if (idx >= BATCH * OUTN * NF) return;
    int f = idx % NF;
    int t = (idx / NF) % OUTN;
    int b = idx / (NF * OUTN);
    const float* yr = h32 + ((long long)b * NODEP + f) * 68;
    float acc = 0.f;
    #pragma unroll
    for (int k = 0; k < DCTN; k++) acc += dctm[k * DCTN + (KQ + t)] * yr[k];
    out[idx] = acc;
}

// ---------------- host ----------------
extern "C" void kernel_launch(void* const* d_in, const int* in_sizes, int n_in,
                              void* d_out, int out_size, void* d_ws, size_t ws_size,
                              hipStream_t stream) {
    const float* poses   = (const float*)d_in[0];
    const float* qw1     = (const float*)d_in[1];
    const float* qw2     = (const float*)d_in[2];
    const float* kw1     = (const float*)d_in[3];
    const float* kw2     = (const float*)d_in[4];
    const float* gc1_att = (const float*)d_in[5];
    const float* gc1_w   = (const float*)d_in[6];
    const float* gc1_b   = (const float*)d_in[7];
    const float* bn1_g   = (const float*)d_in[8];
    const float* bn1_b   = (const float*)d_in[9];
    const float* gcb_att = (const float*)d_in[10];
    const float* gcb_w   = (const float*)d_in[11];
    const float* gcb_b   = (const float*)d_in[12];
    const float* gcb_g   = (const float*)d_in[13];
    const float* gcb_beta= (const float*)d_in[14];
    const float* gc7_att = (const float*)d_in[15];
    const float* gc7_w   = (const float*)d_in[16];
    const float* gc7_b   = (const float*)d_in[17];
    float* out = (float*)d_out;
    float* w = (float*)d_ws;

    // ---- workspace layout (f32 units) ----
    float* dct   = w;                      // 1156 -> pad 1280
    float* att   = w + 1280;               // -> 23808
    float* w34   = w + 23808;              // -> 1198848
    float* x32   = w + 1198848;            // RP*68 -> 3566336
    float* h32   = w + 3566336;            // RP*68 -> 5933824
    float* qf    = w + 5933824;            // -> 6064896
    ushort* su   = (ushort*)(w + 6064896); // bf16 weight region
    ushort* WT1    = su;                   // 512*128   = 65536
    ushort* WTb    = su + 65536;           // 4*512*512 = 1048576
    ushort* WT7    = su + 1114112;         // 68*512    = 34816
    ushort* A16_1  = su + 1148928;         // 135*192   = 25920
    ushort* A16_B  = su + 1174848;         // 540*192   = 103680
    ushort* A16_7  = su + 1278528;         // 25920
    float* bnT   = w + 6717120;            // 10 * 69632 -> 7413440
    float* kf    = w + 7413440;            // 256*87*512 -> 18816704
    ushort* R2   = (ushort*)(w + 18816704);
    ushort* yT16  = R2;
    ushort* r1k16 = R2;                    // phase-A alias
    ushort* r1q16 = R2 + 11927552;
    ushort* R3   = (ushort*)(w + 27729600);
    ushort* hT16  = R3;
    ushort* pb16  = R3;                    // phase-A alias
    ushort* Wt1k  = R3 + 5013504;
    ushort* Wt1q  = R3 + 5439488;
    ushort* Wt2k  = R3 + 5865472;
    ushort* Wt2q  = R3 + 7176192;
    ushort* R4   = (ushort*)(w + 36642496);
    ushort* zN16  = R4;
    ushort* xT16  = R4;                    // alias (dead before zN16 written)
    ushort* z116  = R4 + 2367488;          // RP*80
    float* zpadf = w + 45555392;           // 128 f zero page
    const ushort* zpad = (const ushort*)zpadf;

    const int INF_RPB = 1 << 30;

    // ---- fused prep (one dispatch) ----
    prep_all<<<PB_DCT, 256, 0, stream>>>(
        poses, pb16, kw1, qw1, Wt1k, Wt1q, kw2, qw2, Wt2k, Wt2q,
        gc1_w, WT1, gcb_w, WTb, gc7_w, WT7,
        gc1_att, A16_1, gcb_att, A16_B, gc7_att, A16_7,
        bn1_g, bn1_b, gcb_g, gcb_beta, bnT, zpadf, dct);

    // ---- conv stack ----
    // conv1k: BM=128,BN=128; A-stream m-partitioned per XCD (mode 2): 182 m-blocks,
    //         4 n-blocks, Pc=23 -> s=0..91, grid 8*92=736 (mb up to 183 early-return)
    gemm2<128,128><<<dim3(736, 1, 1), 256, 0, stream>>>(pb16, Wt1k, zpad, 23296, 512, 832,
        2, 4, 23, 91, 19584LL, 136LL, 0LL, 832LL, 0LL,
        (float*)nullptr, r1k16, 0LL, 512LL, 1LL, 1, nullptr, 0, nullptr, nullptr, 0, nullptr, nullptr);
    gemm2<128,128><<<dim3(4, 10, 1), 256, 0, stream>>>(pb16 + 110*136, Wt1q, zpad, 1280, 512, 832,
        0, 0, 0, 5, 19584LL, 136LL, 0LL, 832LL, 0LL,
        (float*)nullptr, r1q16, 0LL, 512LL, 1LL, 1, nullptr, 0, nullptr, nullptr, 0, nullptr, nullptr);
    // conv2k: BM=128,BN=128; mode 2: 174 m-blocks, 4 n-blocks, Pc=22 -> grid 8*88=704
    gemm2<128,128><<<dim3(704, 1, 1), 256, 0, stream>>>(r1k16, Wt2k, zpad, 22272, 512, 2560,
        2, 4, 22, 87, 46592LL, 512LL, 0LL, 2560LL, 0LL,
        kf, (ushort*)nullptr, 0LL, 512LL, 1LL, 1, nullptr, 0, nullptr, nullptr, 0, nullptr, nullptr);
    gemm2<64,64><<<dim3(8, 4, 1), 256, 0, stream>>>(r1q16, Wt2q, zpad, 256, 512, 2560,
        0, 0, 0, INF_RPB, 0LL, 2560LL, 0LL, 2560LL, 0LL,
        qf, (ushort*)nullptr, 0LL, 512LL, 1LL, 1, nullptr, 0, nullptr, nullptr, 0, nullptr, nullptr);

    // ---- attention + x ----
    att_k<<<BATCH, 256, 0, stream>>>(kf, qf, att);
    weighted_k<<<dim3(DCTN, BATCH), 192, 0, stream>>>(poses, att, w34);
    build_x<<<(BATCH * NF * 68 + 255) / 256, 256, 0, stream>>>(poses, w34, dct, x32, xT16);

    // ---- gc1: mix then W(68->512) ----
    gemm2<64,64><<<dim3(3, 2, BATCH), 256, 0, stream>>>(xT16, A16_1, zpad, 68, 135, 192,
        0, 0, 0, INF_RPB, 0LL, (long long)RP, 136LL, 192LL, 0LL,
        (float*)nullptr, z116, 10880LL, 1LL, 80LL, 0, nullptr, 0, nullptr, nullptr, 0, nullptr, nullptr);
    // gc1 W: BM=128,BN=128; mode 1: 4 m-blocks, 272 n-blocks, Pc=34 -> grid 8*136=1088
    gemm2<128,128><<<dim3(1088, 1, 1), 256, 0, stream>>>(WT1, z116, zpad, 512, RP, 128,
        1, 4, 34, INF_RPB, 0LL, 128LL, 0LL, 80LL, 0LL,
        (float*)nullptr, yT16, 0LL, (long long)RP, 1LL, 0, gc1_b, 1, bnT, bnT + 69632, 1, nullptr, nullptr);

    // ---- residual GCN blocks ----
    for (int L = 0; L < 4; L++) {
        const ushort* min = (L & 1) ? hT16 : yT16;
        gemm2<64,64><<<dim3(3, 8, BATCH), 256, 0, stream>>>(min, A16_B + L*25920, zpad, 512, 135, 192,
            0, 0, 0, INF_RPB, 0LL, (long long)RP, 136LL, 192LL, 0LL,
            (float*)nullptr, zN16, 69632LL, 1LL, 512LL, 0, nullptr, 0, nullptr, nullptr, 0, nullptr, nullptr);
        // W: BM=128,BN=128; mode 1: 4 m-blocks, Pc=34 -> grid 1088
        gemm2<128,128><<<dim3(1088, 1, 1), 256, 0, stream>>>(WTb + L*262144, zN16, zpad, 512, RP, 512,
            1, 4, 34, INF_RPB, 0LL, 512LL, 0LL, 512LL, 0LL,
            (float*)nullptr, (L & 1) ? yT16 : hT16, 0LL, (long long)RP, 1LL,
            0, gcb_b + L*512, 1, bnT + (1 + L) * 139264, bnT + (1 + L) * 139264 + 69632, 1,
            (L & 1) ? yT16 : (const ushort*)nullptr, nullptr);
    }

    // ---- gc7: mix then W(512->68) + bias + x residual ----
    gemm2<64,64><<<dim3(3, 8, BATCH), 256, 0, stream>>>(yT16, A16_7, zpad, 512, 135, 192,
        0, 0, 0, INF_RPB, 0LL, (long long)RP, 136LL, 192LL, 0LL,
        (float*)nullptr, zN16, 69632LL, 1LL, 512LL, 0, nullptr, 0, nullptr, nullptr, 0, nullptr, nullptr);
    // gc7 W: BM=128,BN=64; A-stream m-partitioned (mode 2): 272 m-blocks, 2 n-blocks,
    //        Pc=34 -> s=0..67, grid 8*68=544
    gemm2<128,64><<<dim3(544, 1, 1), 256, 0, stream>>>(zN16, WT7, zpad, RP, 68, 512,
        2, 2, 34, INF_RPB, 0LL, 512LL, 0LL, 512LL, 0LL,
        h32, (ushort*)nullptr, 0LL, 68LL, 1LL, 0, gc7_b, 2, nullptr, nullptr, 0, nullptr, x32);

    idct_out<<<(BATCH * OUTN * NF + 255) / 256, 256, 0, stream>>>(h32, dct, out);
}

// Round 5
// 1046.444 us; speedup vs baseline: 1.4301x; 1.0361x over previous
//
#include <hip/hip_runtime.h>
#include <math.h>

// ---------------- problem constants ----------------
#define POSE_ROWS 144
#define NF 135
#define DD 512
#define KQ 10
#define DCTN 34
#define INN 120
#define OUTN 24
#define VN 87
#define BATCH 256
#define RP 34816              // padded row dim: 256 * 136
#define NODEP 136
#define BN_SCALE 0.9999950000374997f

typedef __attribute__((ext_vector_type(8))) short short8;
typedef __attribute__((ext_vector_type(4))) float floatx4;

static __device__ __forceinline__ ushort f2bf(float f) {
    unsigned u = __builtin_bit_cast(unsigned, f);
    u = (u + 0x7FFFu + ((u >> 16) & 1u)) >> 16;
    return (ushort)u;
}
static __device__ __forceinline__ float bf2f(ushort s) {
    return __builtin_bit_cast(float, (unsigned)s << 16);
}
// fast tanh via exp2
static __device__ __forceinline__ float tanh_fast(float x) {
    float ax = __builtin_fabsf(x);
    float e = __builtin_amdgcn_exp2f(ax * -2.885390081777927f);   // e^{-2ax}
    float t = (1.f - e) * __builtin_amdgcn_rcpf(1.f + e);
    return __builtin_copysignf(t, x);
}

#define GLOAD_LDS(gp, lp) __builtin_amdgcn_global_load_lds( \
    (const __attribute__((address_space(1))) unsigned int*)(const void*)(gp), \
    (__attribute__((address_space(3))) unsigned int*)(void*)(lp), 16, 0, 0)

// ---------------- fused prep kernel (all weight repacks / converts in ONE dispatch) ----
#define PB_POSES 19584
#define PB_K1B   22912
#define PB_K2B   33152
#define PB_WT1   33408
#define PB_WTB   37504
#define PB_WT7   37640
#define PB_A1    37742
#define PB_AB    38147
#define PB_A7    38249
#define PB_BN    39609
#define PB_Z     39610
#define PB_DCT   39615

__global__ __launch_bounds__(256) void prep_all(
    const float* __restrict__ poses, ushort* __restrict__ pb16,
    const float* __restrict__ kw1, const float* __restrict__ qw1,
    ushort* __restrict__ Wt1k, ushort* __restrict__ Wt1q,
    const float* __restrict__ kw2, const float* __restrict__ qw2,
    ushort* __restrict__ Wt2k, ushort* __restrict__ Wt2q,
    const float* __restrict__ gc1_w, ushort* __restrict__ WT1,
    const float* __restrict__ gcb_w, ushort* __restrict__ WTb,
    const float* __restrict__ gc7_w, ushort* __restrict__ WT7,
    const float* __restrict__ gc1_att, ushort* __restrict__ A16_1,
    const float* __restrict__ gcb_att, ushort* __restrict__ A16_B,
    const float* __restrict__ gc7_att, ushort* __restrict__ A16_7,
    const float* __restrict__ bn1_g, const float* __restrict__ bn1_b,
    const float* __restrict__ gcb_g, const float* __restrict__ gcb_beta,
    float* __restrict__ bnT, float* __restrict__ zpadf, float* __restrict__ dct)
{
    const int blk = blockIdx.x;
    const int tid = threadIdx.x;
    if (blk < PB_POSES) {
        int idx = blk * 256 + tid;
        int i = idx % NODEP;
        int row = (idx / NODEP) % POSE_ROWS;
        int b = idx / (NODEP * POSE_ROWS);
        float v = (i < NF) ? poses[((long long)b * POSE_ROWS + row) * NF + i] * 1e-3f : 0.f;
        pb16[idx] = f2bf(v);
    } else if (blk < PB_K1B) {
        int wi = blk - PB_POSES;
        const float* src = (wi < 1664) ? kw1 : qw1;
        ushort* dst = (wi < 1664) ? Wt1k : Wt1q;
        int idx = (wi % 1664) * 256 + tid;
        int n = idx / 832, k = idx % 832;
        int h = k / 136, i = k % 136;
        float v = (i < 135 && h < 6) ? src[((long long)n * 135 + i) * 6 + h] : 0.f;
        dst[idx] = f2bf(v);
    } else if (blk < PB_K2B) {
        int wi = blk - PB_K1B;
        const float* src = (wi < 5120) ? kw2 : qw2;
        ushort* dst = (wi < 5120) ? Wt2k : Wt2q;
        int idx = (wi % 5120) * 256 + tid;
        int n = idx / 2560, k = idx % 2560;
        int h = k / 512, i = k % 512;
        dst[idx] = f2bf(src[((long long)n * 512 + i) * 5 + h]);
    } else if (blk < PB_WT1) {
        int idx = (blk - PB_K2B) * 256 + tid;
        int n = idx / 128, k = idx % 128;
        WT1[idx] = f2bf((k < 68) ? gc1_w[(long long)k * 512 + n] : 0.f);
    } else if (blk < PB_WTB) {
        int g = (blk - PB_WT1) * 256 + tid;
        int L = g >> 18, idx = g & 262143;
        int n = idx / 512, k = idx % 512;
        WTb[g] = f2bf(gcb_w[(long long)L * 262144 + (long long)k * 512 + n]);
    } else if (blk < PB_WT7) {
        int idx = (blk - PB_WTB) * 256 + tid;
        int n = idx / 512, k = idx % 512;
        WT7[idx] = f2bf(gc7_w[(long long)k * 68 + n]);
    } else if (blk < PB_A1) {
        int idx = (blk - PB_WT7) * 256 + tid;
        if (idx < 135 * 192) {
            int r = idx / 192, c = idx % 192;
            A16_1[idx] = f2bf(c < 135 ? gc1_att[r * 135 + c] : 0.f);
        }
    } else if (blk < PB_AB) {
        int idx = (blk - PB_A1) * 256 + tid;
        int r = idx / 192, c = idx % 192;
        A16_B[idx] = f2bf(c < 135 ? gcb_att[r * 135 + c] : 0.f);
    } else if (blk < PB_A7) {
        int idx = (blk - PB_AB) * 256 + tid;
        if (idx < 135 * 192) {
            int r = idx / 192, c = idx % 192;
            A16_7[idx] = f2bf(c < 135 ? gc7_att[r * 135 + c] : 0.f);
        }
    } else if (blk < PB_BN) {
        int g = (blk - PB_A7) * 256 + tid;
        int p = g / 69632, idx = g % 69632;
        int node = idx % 136, m = idx / 136;
        const float* gs = (p == 0) ? bn1_g : (gcb_g + (p - 1) * 69120);
        const float* bs = (p == 0) ? bn1_b : (gcb_beta + (p - 1) * 69120);
        float* gt = bnT + (long long)p * 139264;
        float* bt = gt + 69632;
        gt[idx] = (node < 135) ? gs[node * 512 + m] : 0.f;
        bt[idx] = (node < 135) ? bs[node * 512 + m] : 0.f;
    } else if (blk < PB_Z) {
        if (tid < 128) zpadf[tid] = 0.f;
    } else {
        int idx = (blk - PB_Z) * 256 + tid;
        if (idx < DCTN * DCTN) {
            int k = idx / DCTN, i = idx % DCTN;
            double w = (k == 0) ? sqrt(1.0 / DCTN) : sqrt(2.0 / DCTN);
            dct[idx] = (float)(w * cos(3.14159265358979323846 * (i + 0.5) * k / (double)DCTN));
        }
    }
}

// ---------------- NT MFMA GEMM, BK=64, global_load_lds staging, XOR-swizzled LDS ----------
// XCD-aware block mapping:
//   mode 0: mb = blockIdx.y, nb = blockIdx.x
//   mode 1: n-partitioned per XCD (stream = B): x=gx&7; s=gx>>3; mb=s%CNT; nb=x*Pc+s/CNT
//   mode 2: m-partitioned per XCD (stream = A): x=gx&7; s=gx>>3; nb=s%CNT; mb=x*Pc+s/CNT
template<int BM, int BN>
__global__ __launch_bounds__(256) void gemm2(
    const ushort* __restrict__ A, const ushort* __restrict__ Bt,
    const ushort* __restrict__ zpad,
    int M, int N, int K,
    int mode, int CNT, int Pc,
    int rpbA, long long sAw, long long sAr, long long sAbz,
    long long sBr, long long sBbz,
    float* __restrict__ C, ushort* __restrict__ C16,
    long long sCbz, long long sCm, long long sCn,
    int do_relu, const float* __restrict__ bias, int bias_mode,
    const float* __restrict__ bnTg, const float* __restrict__ bnTb,
    int do_tanh, const ushort* __restrict__ resid16, const float* __restrict__ resid32)
{
    constexpr int SM = BM / 32, SN = BN / 32;
    constexpr int RA = BM / 32, RB = BN / 32;     // staging rounds, 32 rows each
    __shared__ ushort As[BM * 64];
    __shared__ ushort Bs[BN * 64];

    int mb, nb;
    if (mode == 0) { mb = blockIdx.y; nb = blockIdx.x; }
    else {
        int gx = blockIdx.x;
        int x = gx & 7, s = gx >> 3;
        if (mode == 1) { mb = s % CNT; nb = x * Pc + s / CNT; }
        else           { nb = s % CNT; mb = x * Pc + s / CNT; }
    }
    const int m0 = mb * BM, n0 = nb * BN;
    if (m0 >= M || n0 >= N) return;          // block-uniform: safe before barriers

    const int tid = threadIdx.x;
    const int lane = tid & 63, w = tid >> 6;
    const int bz = blockIdx.z;
    const int wm = (w >> 1) * (BM / 2), wn = (w & 1) * (BN / 2);
    const int chunk = (lane & 7) ^ ((lane >> 3) & 7);

    const ushort* pA[RA]; int stA[RA];
    #pragma unroll
    for (int j = 0; j < RA; j++) {
        int m = m0 + j * 32 + w * 8 + (lane >> 3);
        bool v = m < M;
        long long off = v ? ((long long)(m / rpbA) * sAw + (long long)(m % rpbA) * sAr
                            + (long long)bz * sAbz) : 0;
        pA[j] = v ? (A + off + chunk * 8) : (zpad + chunk * 8);
        stA[j] = v ? 64 : 0;
    }
    const ushort* pB[RB]; int stB[RB];
    #pragma unroll
    for (int j = 0; j < RB; j++) {
        int n = n0 + j * 32 + w * 8 + (lane >> 3);
        bool v = n < N;
        long long off = v ? ((long long)n * sBr + (long long)bz * sBbz) : 0;
        pB[j] = v ? (Bt + off + chunk * 8) : (zpad + chunk * 8);
        stB[j] = v ? 64 : 0;
    }

    floatx4 acc[SM][SN];
    #pragma unroll
    for (int i = 0; i < SM; i++)
        #pragma unroll
        for (int j = 0; j < SN; j++)
            acc[i][j] = (floatx4){0.f, 0.f, 0.f, 0.f};

    for (int k0 = 0; k0 < K; k0 += 64) {
        #pragma unroll
        for (int j = 0; j < RA; j++)
            GLOAD_LDS(pA[j], &As[(j * 32 + w * 8) * 64]);
        #pragma unroll
        for (int j = 0; j < RB; j++)
            GLOAD_LDS(pB[j], &Bs[(j * 32 + w * 8) * 64]);
        __syncthreads();

        #pragma unroll
        for (int kk = 0; kk < 2; kk++) {
            short8 af[SM], bf[SN];
            #pragma unroll
            for (int sm = 0; sm < SM; sm++) {
                int lr = wm + sm * 16 + (lane & 15);
                int slot = ((lane >> 4) + kk * 4) ^ (lr & 7);
                af[sm] = *(const short8*)&As[lr * 64 + slot * 8];
            }
            #pragma unroll
            for (int sn = 0; sn < SN; sn++) {
                int lr = wn + sn * 16 + (lane & 15);
                int slot = ((lane >> 4) + kk * 4) ^ (lr & 7);
                bf[sn] = *(const short8*)&Bs[lr * 64 + slot * 8];
            }
            #pragma unroll
            for (int sm = 0; sm < SM; sm++)
                #pragma unroll
                for (int sn = 0; sn < SN; sn++)
                    acc[sm][sn] = __builtin_amdgcn_mfma_f32_16x16x32_bf16(af[sm], bf[sn], acc[sm][sn], 0, 0, 0);
        }
        __syncthreads();

        #pragma unroll
        for (int j = 0; j < RA; j++) pA[j] += stA[j];
        #pragma unroll
        for (int j = 0; j < RB; j++) pB[j] += stB[j];
    }

    // epilogue: D mapping col(n)=lane&15, row(m)=(lane>>4)*4+r
    const int lc = lane & 15;
    const int lr4 = (lane >> 4) << 2;
    #pragma unroll
    for (int sm = 0; sm < SM; sm++) {
        #pragma unroll
        for (int sn = 0; sn < SN; sn++) {
            int n = n0 + wn + sn * 16 + lc;
            if (n >= N) continue;
            int node = n % 136;
            int mbv = m0 + wm + sm * 16 + lr4;
            float vv[4];
            #pragma unroll
            for (int r = 0; r < 4; r++) {
                int m = mbv + r;
                float v = acc[sm][sn][r];
                if (do_relu) v = fmaxf(v, 0.f);
                if (bias) v += (bias_mode == 1) ? bias[m < M ? m : 0] : bias[n];
                if (bnTg) {
                    long long gi = (long long)(m < M ? m : 0) * 136 + node;
                    v = bnTg[gi] * (v * BN_SCALE) + bnTb[gi];
                }
                if (do_tanh) v = tanh_fast(v);
                long long addr = (long long)bz * sCbz + (long long)m * sCm + (long long)n * sCn;
                if (m < M) {
                    if (resid16) v += bf2f(resid16[addr]);
                    else if (resid32) v += resid32[addr];
                    if (C) C[addr] = v;
                    if (C16 && sCm != 1) C16[addr] = f2bf(v);
                }
                vv[r] = v;
            }
            if (C16 && sCm == 1 && mbv + 3 < M) {
                ushort4 pk;
                pk.x = f2bf(vv[0]); pk.y = f2bf(vv[1]); pk.z = f2bf(vv[2]); pk.w = f2bf(vv[3]);
                *(ushort4*)&C16[(long long)bz * sCbz + mbv + (long long)n * sCn] = pk;
            }
        }
    }
}

// ---------------- B-register-streamed GEMM: BM=128, BN=64, mode-1 mapping -----------
// For GEMMs whose B operand is a stream-once, L2-missing panel (the latency
// bottleneck): B fragments are loaded DIRECTLY into registers, pipelined 2
// K-steps deep (3 static register sets, fully unrolled), never stalled by any
// barrier. A (L2-resident weights) keeps double-buffered LDS staging with a
// per-wave COUNTED vmcnt + raw s_barrier — no vmcnt(0) drain in the loop.
//   iter t: stage A(t+1)->As[cur^1] | load B(t+2)->br[(t+2)%3] | compute t
//           | vmcnt(4)  (completes A(t+1)+B(t+1), leaves B(t+2) in flight)
//           | s_barrier
// The counted waits guarantee LDS correctness regardless of how the compiler
// splits the B loads: A's gload_lds are always the oldest ops at the wait.
// Output layout matches round-0: addr = m*sCm + n (sCm = RP), scalar stores.
template<int NS>
__global__ __launch_bounds__(256, 3) void gemm_bs(
    const ushort* __restrict__ A, const ushort* __restrict__ Bt,
    int CNT, int Pc,
    long long sAr, long long sBr,
    ushort* __restrict__ C16, long long sCm,
    const float* __restrict__ bias,
    const float* __restrict__ bnTg, const float* __restrict__ bnTb,
    const ushort* __restrict__ resid16)
{
    __shared__ ushort As[2][128 * 64];

    const int gx = blockIdx.x;
    const int x = gx & 7, s = gx >> 3;
    const int mb = s % CNT, nb = x * Pc + s / CNT;
    const int m0 = mb * 128, n0 = nb * 64;

    const int tid = threadIdx.x;
    const int lane = tid & 63, w = tid >> 6;
    const int wm = (w >> 1) * 64, wn = (w & 1) * 32;
    const int chunk = (lane & 7) ^ ((lane >> 3) & 7);

    // A staging pointers (per thread, 4 rows of 32)
    const ushort* pA[4];
    #pragma unroll
    for (int j = 0; j < 4; j++) {
        int m = m0 + j * 32 + w * 8 + (lane >> 3);
        pA[j] = A + (long long)m * sAr + chunk * 8;
    }
    // B fragment base pointers (per thread, SN=2)
    const ushort* pB[2];
    #pragma unroll
    for (int sn = 0; sn < 2; sn++)
        pB[sn] = Bt + (long long)(n0 + wn + sn * 16 + (lane & 15)) * sBr + (lane >> 4) * 8;

    short8 br[3][2][2];
    floatx4 acc[4][2];
    #pragma unroll
    for (int i = 0; i < 4; i++)
        #pragma unroll
        for (int j = 0; j < 2; j++)
            acc[i][j] = (floatx4){0.f, 0.f, 0.f, 0.f};

    // ---- prologue: A(0); B(0); B(1); counted wait; barrier ----
    #pragma unroll
    for (int j = 0; j < 4; j++)
        GLOAD_LDS(pA[j], &As[0][(j * 32 + w * 8) * 64]);
    __builtin_amdgcn_sched_barrier(0);
    #pragma unroll
    for (int sn = 0; sn < 2; sn++)
        #pragma unroll
        for (int kk = 0; kk < 2; kk++)
            br[0][sn][kk] = *(const short8*)(pB[sn] + kk * 32);
    if (NS > 1) {
        #pragma unroll
        for (int sn = 0; sn < 2; sn++)
            #pragma unroll
            for (int kk = 0; kk < 2; kk++)
                br[1][sn][kk] = *(const short8*)(pB[sn] + 64 + kk * 32);
    }
    __builtin_amdgcn_sched_barrier(0);
    if (NS > 1) { asm volatile("s_waitcnt vmcnt(4)" ::: "memory"); }
    else        { asm volatile("s_waitcnt vmcnt(0)" ::: "memory"); }
    __builtin_amdgcn_sched_barrier(0);
    __builtin_amdgcn_s_barrier();
    __builtin_amdgcn_sched_barrier(0);

    #pragma unroll
    for (int t = 0; t < NS; t++) {
        const int cur = t & 1;
        // stage A(t+1) into the other LDS buffer
        if (t + 1 < NS) {
            #pragma unroll
            for (int j = 0; j < 4; j++)
                GLOAD_LDS(pA[j] + (t + 1) * 64, &As[cur ^ 1][(j * 32 + w * 8) * 64]);
        }
        __builtin_amdgcn_sched_barrier(0);
        // issue B(t+2) into its register set (deepest prefetch; never drained)
        if (t + 2 < NS) {
            #pragma unroll
            for (int sn = 0; sn < 2; sn++)
                #pragma unroll
                for (int kk = 0; kk < 2; kk++)
                    br[(t + 2) % 3][sn][kk] = *(const short8*)(pB[sn] + (t + 2) * 64 + kk * 32);
        }
        __builtin_amdgcn_sched_barrier(0);
        // compute tile t from As[cur] + br[t%3]
        #pragma unroll
        for (int kk = 0; kk < 2; kk++) {
            short8 af[4];
            #pragma unroll
            for (int sm = 0; sm < 4; sm++) {
                int lr = wm + sm * 16 + (lane & 15);
                int slot = ((lane >> 4) + kk * 4) ^ (lr & 7);
                af[sm] = *(const short8*)&As[cur][lr * 64 + slot * 8];
            }
            #pragma unroll
            for (int sm = 0; sm < 4; sm++)
                #pragma unroll
                for (int sn = 0; sn < 2; sn++)
                    acc[sm][sn] = __builtin_amdgcn_mfma_f32_16x16x32_bf16(
                        af[sm], br[t % 3][sn][kk], acc[sm][sn], 0, 0, 0);
        }
        if (t + 1 < NS) {
            __builtin_amdgcn_sched_barrier(0);
            // completes A(t+1) (oldest in queue); leaves B(t+2) in flight
            if (t + 2 < NS) { asm volatile("s_waitcnt vmcnt(4)" ::: "memory"); }
            else            { asm volatile("s_waitcnt vmcnt(0)" ::: "memory"); }
            __builtin_amdgcn_sched_barrier(0);
            __builtin_amdgcn_s_barrier();
            __builtin_amdgcn_sched_barrier(0);
        }
    }

    // ---- epilogue: bias[m] + bn + tanh (+resid16); addr = m*sCm + n (round-0 layout) ----
    const int lc = lane & 15;
    const int lr4 = (lane >> 4) << 2;
    #pragma unroll
    for (int sm = 0; sm < 4; sm++) {
        #pragma unroll
        for (int sn = 0; sn < 2; sn++) {
            int n = n0 + wn + sn * 16 + lc;
            int node = n % 136;
            int mbv = m0 + wm + sm * 16 + lr4;
            #pragma unroll
            for (int r = 0; r < 4; r++) {
                int m = mbv + r;
                float v = acc[sm][sn][r];
                v += bias[m];
                long long gi = (long long)m * 136 + node;
                v = bnTg[gi] * (v * BN_SCALE) + bnTb[gi];
                v = tanh_fast(v);
                long long addr = (long long)m * sCm + n;
                if (resid16) v += bf2f(resid16[addr]);
                C16[addr] = f2bf(v);
            }
        }
    }
}

// ---------------- attention scores + normalize (wave-parallel) ----------------
__global__ __launch_bounds__(256) void att_k(const float* __restrict__ kf, const float* __restrict__ qf,
                                             float* __restrict__ att) {
    int b = blockIdx.x;
    int tid = threadIdx.x;
    int lane = tid & 63, w = tid >> 6;
    __shared__ float s[96];
    __shared__ float ssum;
    const float* qb = qf + b * DD + lane * 8;
    float4 q0 = *(const float4*)qb;
    float4 q1 = *(const float4*)(qb + 4);
    const float* kb = kf + (long long)b * VN * DD;
    for (int v = w; v < VN; v += 4) {
        const float* kr = kb + v * DD + lane * 8;
        float4 k0 = *(const float4*)kr;
        float4 k1 = *(const float4*)(kr + 4);
        float p = q0.x * k0.x + q0.y * k0.y + q0.z * k0.z + q0.w * k0.w
                + q1.x * k1.x + q1.y * k1.y + q1.z * k1.z + q1.w * k1.w;
        #pragma unroll
        for (int off = 32; off; off >>= 1) p += __shfl_xor(p, off);
        if (lane == 0) s[v] = p + 1e-15f;
    }
    __syncthreads();
    if (tid < 64) {
        float p2 = (tid < VN ? s[tid] : 0.f) + ((tid + 64) < VN ? s[tid + 64] : 0.f);
        #pragma unroll
        for (int off = 32; off; off >>= 1) p2 += __shfl_xor(p2, off);
        if (tid == 0) ssum = p2;
    }
    __syncthreads();
    float inv = 1.f / ssum;
    for (int v = tid; v < VN; v += 256) att[b * VN + v] = s[v] * inv;
}

// ---------------- w34[b,t,f] = sum_v att[b,v] * poses[b,v+t,f] ----------------
__global__ void weighted_k(const float* __restrict__ poses, const float* __restrict__ att,
                           float* __restrict__ w34) {
    int t = blockIdx.x;
    int b = blockIdx.y;
    int f = threadIdx.x;
    if (f >= NF) return;
    const float* pb = poses + (long long)b * POSE_ROWS * NF + t * NF + f;
    const float* ab = att + b * VN;
    float acc = 0.f;
    for (int v = 0; v < VN; v++) acc += ab[v] * pb[v * NF];
    w34[(long long)b * DCTN * NF + t * NF + f] = acc;
}

// ---------------- x = concat(dct_in, dct_att); node-major f32 + feature-major bf16 ----
__global__ void build_x(const float* __restrict__ poses, const float* __restrict__ w34,
                        const float* __restrict__ dctm, float* __restrict__ x32,
                        ushort* __restrict__ xT16) {
    int idx = blockIdx.x * 256 + threadIdx.x;
    if (idx >= BATCH * NF * 68) return;
    int kk = idx % 68;
    int f = (idx / 68) % NF;
    int b = idx / (68 * NF);
    float acc = 0.f;
    if (kk < DCTN) {
        const float* pb = poses + (long long)b * POSE_ROWS * NF;
        #pragma unroll
        for (int t = 0; t < DCTN; t++) {
            int row = (t < KQ) ? (INN - KQ + t) : (INN - 1);
            acc += dctm[kk * DCTN + t] * pb[row * NF + f];
        }
    } else {
        int k2 = kk - DCTN;
        const float* wb = w34 + (long long)b * DCTN * NF + f;
        #pragma unroll
        for (int t = 0; t < DCTN; t++) acc += dctm[k2 * DCTN + t] * wb[t * NF];
    }
    long long R = (long long)b * NODEP + f;
    x32[R * 68 + kk] = acc;
    xT16[(long long)kk * RP + R] = f2bf(acc);
}

// ---------------- preds[b,t,f] = sum_k dct[k][10+t] * h32[(b*136+f)*68+k] ----------------
__global__ void idct_out(const float* __restrict__ h32, const float* __restrict__ dctm,
                         float* __restrict__ out) {
    int idx = blockIdx.x * 256 + threadIdx.x;
    if (idx >= BATCH * OUTN * NF) return;
    int f = idx % NF;
    int t = (idx / NF) % OUTN;
    int b = idx / (NF * OUTN);
    const float* yr = h32 + ((long long)b * NODEP + f) * 68;
    float acc = 0.f;
    #pragma unroll
    for (int k = 0; k < DCTN; k++) acc += dctm[k * DCTN + (KQ + t)] * yr[k];
    out[idx] = acc;
}

// ---------------- host ----------------
extern "C" void kernel_launch(void* const* d_in, const int* in_sizes, int n_in,
                              void* d_out, int out_size, void* d_ws, size_t ws_size,
                              hipStream_t stream) {
    const float* poses   = (const float*)d_in[0];
    const float* qw1     = (const float*)d_in[1];
    const float* qw2     = (const float*)d_in[2];
    const float* kw1     = (const float*)d_in[3];
    const float* kw2     = (const float*)d_in[4];
    const float* gc1_att = (const float*)d_in[5];
    const float* gc1_w   = (const float*)d_in[6];
    const float* gc1_b   = (const float*)d_in[7];
    const float* bn1_g   = (const float*)d_in[8];
    const float* bn1_b   = (const float*)d_in[9];
    const float* gcb_att = (const float*)d_in[10];
    const float* gcb_w   = (const float*)d_in[11];
    const float* gcb_b   = (const float*)d_in[12];
    const float* gcb_g   = (const float*)d_in[13];
    const float* gcb_beta= (const float*)d_in[14];
    const float* gc7_att = (const float*)d_in[15];
    const float* gc7_w   = (const float*)d_in[16];
    const float* gc7_b   = (const float*)d_in[17];
    float* out = (float*)d_out;
    float* w = (float*)d_ws;

    // ---- workspace layout (f32 units) ----
    float* dct   = w;                      // 1156 -> pad 1280
    float* att   = w + 1280;               // -> 23808
    float* w34   = w + 23808;              // -> 1198848
    float* x32   = w + 1198848;            // RP*68 -> 3566336
    float* h32   = w + 3566336;            // RP*68 -> 5933824
    float* qf    = w + 5933824;            // -> 6064896
    ushort* su   = (ushort*)(w + 6064896); // bf16 weight region
    ushort* WT1    = su;                   // 512*128   = 65536
    ushort* WTb    = su + 65536;           // 4*512*512 = 1048576
    ushort* WT7    = su + 1114112;         // 68*512    = 34816
    ushort* A16_1  = su + 1148928;         // 135*192   = 25920
    ushort* A16_B  = su + 1174848;         // 540*192   = 103680
    ushort* A16_7  = su + 1278528;         // 25920
    float* bnT   = w + 6717120;            // 10 * 69632 -> 7413440
    float* kf    = w + 7413440;            // 256*87*512 -> 18816704
    ushort* R2   = (ushort*)(w + 18816704);
    ushort* yT16  = R2;
    ushort* r1k16 = R2;                    // phase-A alias
    ushort* r1q16 = R2 + 11927552;
    ushort* R3   = (ushort*)(w + 27729600);
    ushort* hT16  = R3;
    ushort* pb16  = R3;                    // phase-A alias
    ushort* Wt1k  = R3 + 5013504;
    ushort* Wt1q  = R3 + 5439488;
    ushort* Wt2k  = R3 + 5865472;
    ushort* Wt2q  = R3 + 7176192;
    ushort* R4   = (ushort*)(w + 36642496);
    ushort* zN16  = R4;
    ushort* xT16  = R4;                    // alias (dead before zN16 written)
    ushort* z116  = R4 + 2367488;          // RP*80
    float* zpadf = w + 45555392;           // 128 f zero page
    const ushort* zpad = (const ushort*)zpadf;

    const int INF_RPB = 1 << 30;

    // ---- fused prep (one dispatch) ----
    prep_all<<<PB_DCT, 256, 0, stream>>>(
        poses, pb16, kw1, qw1, Wt1k, Wt1q, kw2, qw2, Wt2k, Wt2q,
        gc1_w, WT1, gcb_w, WTb, gc7_w, WT7,
        gc1_att, A16_1, gcb_att, A16_B, gc7_att, A16_7,
        bn1_g, bn1_b, gcb_g, gcb_beta, bnT, zpadf, dct);

    // ---- conv stack ----
    // conv1k: BM=128,BN=64; A-stream m-partitioned per XCD (mode 2): 182 m-blocks, Pc=23
    gemm2<128,64><<<dim3(1472, 1, 1), 256, 0, stream>>>(pb16, Wt1k, zpad, 23296, 512, 832,
        2, 8, 23, 91, 19584LL, 136LL, 0LL, 832LL, 0LL,
        (float*)nullptr, r1k16, 0LL, 512LL, 1LL, 1, nullptr, 0, nullptr, nullptr, 0, nullptr, nullptr);
    gemm2<128,128><<<dim3(4, 10, 1), 256, 0, stream>>>(pb16 + 110*136, Wt1q, zpad, 1280, 512, 832,
        0, 0, 0, 5, 19584LL, 136LL, 0LL, 832LL, 0LL,
        (float*)nullptr, r1q16, 0LL, 512LL, 1LL, 1, nullptr, 0, nullptr, nullptr, 0, nullptr, nullptr);
    // conv2k: BM=128,BN=64; mode 2: 174 m-blocks, Pc=22
    gemm2<128,64><<<dim3(1408, 1, 1), 256, 0, stream>>>(r1k16, Wt2k, zpad, 22272, 512, 2560,
        2, 8, 22, 87, 46592LL, 512LL, 0LL, 2560LL, 0LL,
        kf, (ushort*)nullptr, 0LL, 512LL, 1LL, 1, nullptr, 0, nullptr, nullptr, 0, nullptr, nullptr);
    gemm2<64,64><<<dim3(8, 4, 1), 256, 0, stream>>>(r1q16, Wt2q, zpad, 256, 512, 2560,
        0, 0, 0, INF_RPB, 0LL, 2560LL, 0LL, 2560LL, 0LL,
        qf, (ushort*)nullptr, 0LL, 512LL, 1LL, 1, nullptr, 0, nullptr, nullptr, 0, nullptr, nullptr);

    // ---- attention + x ----
    att_k<<<BATCH, 256, 0, stream>>>(kf, qf, att);
    weighted_k<<<dim3(DCTN, BATCH), 192, 0, stream>>>(poses, att, w34);
    build_x<<<(BATCH * NF * 68 + 255) / 256, 256, 0, stream>>>(poses, w34, dct, x32, xT16);

    // ---- gc1: mix then W(68->512) ----
    gemm2<64,64><<<dim3(3, 2, BATCH), 256, 0, stream>>>(xT16, A16_1, zpad, 68, 135, 192,
        0, 0, 0, INF_RPB, 0LL, (long long)RP, 136LL, 192LL, 0LL,
        (float*)nullptr, z116, 10880LL, 1LL, 80LL, 0, nullptr, 0, nullptr, nullptr, 0, nullptr, nullptr);
    // gc1 W: B-reg streamer, K=128 (NS=2); mode-1 mapping: 4 m-blocks, Pc=68, grid 2176
    gemm_bs<2><<<dim3(2176, 1, 1), 256, 0, stream>>>(WT1, z116,
        4, 68, 128LL, 80LL, yT16, (long long)RP, gc1_b, bnT, bnT + 69632, nullptr);

    // ---- residual GCN blocks ----
    for (int L = 0; L < 4; L++) {
        const ushort* min = (L & 1) ? hT16 : yT16;
        gemm2<64,64><<<dim3(3, 8, BATCH), 256, 0, stream>>>(min, A16_B + L*25920, zpad, 512, 135, 192,
            0, 0, 0, INF_RPB, 0LL, (long long)RP, 136LL, 192LL, 0LL,
            (float*)nullptr, zN16, 69632LL, 1LL, 512LL, 0, nullptr, 0, nullptr, nullptr, 0, nullptr, nullptr);
        // W: B-reg streamer, K=512 (NS=8); mode-1 mapping: 4 m-blocks, Pc=68, grid 2176
        gemm_bs<8><<<dim3(2176, 1, 1), 256, 0, stream>>>(WTb + L*262144, zN16,
            4, 68, 512LL, 512LL, (L & 1) ? yT16 : hT16, (long long)RP,
            gcb_b + L*512, bnT + (1 + L) * 139264, bnT + (1 + L) * 139264 + 69632,
            (L & 1) ? yT16 : (const ushort*)nullptr);
    }

    // ---- gc7: mix then W(512->68) + bias + x residual ----
    gemm2<64,64><<<dim3(3, 8, BATCH), 256, 0, stream>>>(yT16, A16_7, zpad, 512, 135, 192,
        0, 0, 0, INF_RPB, 0LL, (long long)RP, 136LL, 192LL, 0LL,
        (float*)nullptr, zN16, 69632LL, 1LL, 512LL, 0, nullptr, 0, nullptr, nullptr, 0, nullptr, nullptr);
    // gc7 W: BM=64,BN=64; A-stream m-partitioned per XCD (mode 2): NBc=2, Pc=68
    gemm2<64,64><<<dim3(1088, 1, 1), 256, 0, stream>>>(zN16, WT7, zpad, RP, 68, 512,
        2, 2, 68, INF_RPB, 0LL, 512LL, 0LL, 512LL, 0LL,
        h32, (ushort*)nullptr, 0LL, 68LL, 1LL, 0, gc7_b, 2, nullptr, nullptr, 0, nullptr, x32);

    idct_out<<<(BATCH * OUTN * NF + 255) / 256, 256, 0, stream>>>(h32, dct, out);
}

// Round 7
// 1018.822 us; speedup vs baseline: 1.4688x; 1.0271x over previous
//
#include <hip/hip_runtime.h>
#include <math.h>

// ---------------- problem constants ----------------
#define POSE_ROWS 144
#define NF 135
#define DD 512
#define KQ 10
#define DCTN 34
#define INN 120
#define OUTN 24
#define VN 87
#define BATCH 256
#define RP 34816              // padded row dim: 256 * 136
#define NODEP 136
#define BN_SCALE 0.9999950000374997f

typedef __attribute__((ext_vector_type(8))) short short8;
typedef __attribute__((ext_vector_type(4))) float floatx4;

static __device__ __forceinline__ ushort f2bf(float f) {
    unsigned u = __builtin_bit_cast(unsigned, f);
    u = (u + 0x7FFFu + ((u >> 16) & 1u)) >> 16;
    return (ushort)u;
}
static __device__ __forceinline__ float bf2f(ushort s) {
    return __builtin_bit_cast(float, (unsigned)s << 16);
}
// fast tanh via exp2
static __device__ __forceinline__ float tanh_fast(float x) {
    float ax = __builtin_fabsf(x);
    float e = __builtin_amdgcn_exp2f(ax * -2.885390081777927f);   // e^{-2ax}
    float t = (1.f - e) * __builtin_amdgcn_rcpf(1.f + e);
    return __builtin_copysignf(t, x);
}

#define GLOAD_LDS(gp, lp) __builtin_amdgcn_global_load_lds( \
    (const __attribute__((address_space(1))) unsigned int*)(const void*)(gp), \
    (__attribute__((address_space(3))) unsigned int*)(void*)(lp), 16, 0, 0)

// ---------------- fused prep kernel (all weight repacks / converts in ONE dispatch) ----
#define PB_POSES 19584
#define PB_K1B   22912
#define PB_K2B   33152
#define PB_WT1   33408
#define PB_WTB   37504
#define PB_WT7   37640
#define PB_A1    37742
#define PB_AB    38147
#define PB_A7    38249
#define PB_BN    39609
#define PB_Z     39610
#define PB_DCT   39615

__global__ __launch_bounds__(256) void prep_all(
    const float* __restrict__ poses, ushort* __restrict__ pb16,
    const float* __restrict__ kw1, const float* __restrict__ qw1,
    ushort* __restrict__ Wt1k, ushort* __restrict__ Wt1q,
    const float* __restrict__ kw2, const float* __restrict__ qw2,
    ushort* __restrict__ Wt2k, ushort* __restrict__ Wt2q,
    const float* __restrict__ gc1_w, ushort* __restrict__ WT1,
    const float* __restrict__ gcb_w, ushort* __restrict__ WTb,
    const float* __restrict__ gc7_w, ushort* __restrict__ WT7,
    const float* __restrict__ gc1_att, ushort* __restrict__ A16_1,
    const float* __restrict__ gcb_att, ushort* __restrict__ A16_B,
    const float* __restrict__ gc7_att, ushort* __restrict__ A16_7,
    const float* __restrict__ bn1_g, const float* __restrict__ bn1_b,
    const float* __restrict__ gcb_g, const float* __restrict__ gcb_beta,
    float* __restrict__ bnT, float* __restrict__ zpadf, float* __restrict__ dct)
{
    const int blk = blockIdx.x;
    const int tid = threadIdx.x;
    if (blk < PB_POSES) {
        int idx = blk * 256 + tid;
        int i = idx % NODEP;
        int row = (idx / NODEP) % POSE_ROWS;
        int b = idx / (NODEP * POSE_ROWS);
        float v = (i < NF) ? poses[((long long)b * POSE_ROWS + row) * NF + i] * 1e-3f : 0.f;
        pb16[idx] = f2bf(v);
    } else if (blk < PB_K1B) {
        int wi = blk - PB_POSES;
        const float* src = (wi < 1664) ? kw1 : qw1;
        ushort* dst = (wi < 1664) ? Wt1k : Wt1q;
        int idx = (wi % 1664) * 256 + tid;
        int n = idx / 832, k = idx % 832;
        int h = k / 136, i = k % 136;
        float v = (i < 135 && h < 6) ? src[((long long)n * 135 + i) * 6 + h] : 0.f;
        dst[idx] = f2bf(v);
    } else if (blk < PB_K2B) {
        int wi = blk - PB_K1B;
        const float* src = (wi < 5120) ? kw2 : qw2;
        ushort* dst = (wi < 5120) ? Wt2k : Wt2q;
        int idx = (wi % 5120) * 256 + tid;
        int n = idx / 2560, k = idx % 2560;
        int h = k / 512, i = k % 512;
        dst[idx] = f2bf(src[((long long)n * 512 + i) * 5 + h]);
    } else if (blk < PB_WT1) {
        int idx = (blk - PB_K2B) * 256 + tid;
        int n = idx / 128, k = idx % 128;
        WT1[idx] = f2bf((k < 68) ? gc1_w[(long long)k * 512 + n] : 0.f);
    } else if (blk < PB_WTB) {
        int g = (blk - PB_WT1) * 256 + tid;
        int L = g >> 18, idx = g & 262143;
        int n = idx / 512, k = idx % 512;
        WTb[g] = f2bf(gcb_w[(long long)L * 262144 + (long long)k * 512 + n]);
    } else if (blk < PB_WT7) {
        int idx = (blk - PB_WTB) * 256 + tid;
        int n = idx / 512, k = idx % 512;
        WT7[idx] = f2bf(gc7_w[(long long)k * 68 + n]);
    } else if (blk < PB_A1) {
        int idx = (blk - PB_WT7) * 256 + tid;
        if (idx < 135 * 192) {
            int r = idx / 192, c = idx % 192;
            A16_1[idx] = f2bf(c < 135 ? gc1_att[r * 135 + c] : 0.f);
        }
    } else if (blk < PB_AB) {
        int idx = (blk - PB_A1) * 256 + tid;
        int r = idx / 192, c = idx % 192;
        A16_B[idx] = f2bf(c < 135 ? gcb_att[r * 135 + c] : 0.f);
    } else if (blk < PB_A7) {
        int idx = (blk - PB_AB) * 256 + tid;
        if (idx < 135 * 192) {
            int r = idx / 192, c = idx % 192;
            A16_7[idx] = f2bf(c < 135 ? gc7_att[r * 135 + c] : 0.f);
        }
    } else if (blk < PB_BN) {
        int g = (blk - PB_A7) * 256 + tid;
        int p = g / 69632, idx = g % 69632;
        int node = idx % 136, m = idx / 136;
        const float* gs = (p == 0) ? bn1_g : (gcb_g + (p - 1) * 69120);
        const float* bs = (p == 0) ? bn1_b : (gcb_beta + (p - 1) * 69120);
        float* gt = bnT + (long long)p * 139264;
        float* bt = gt + 69632;
        gt[idx] = (node < 135) ? gs[node * 512 + m] : 0.f;
        bt[idx] = (node < 135) ? bs[node * 512 + m] : 0.f;
    } else if (blk < PB_Z) {
        if (tid < 128) zpadf[tid] = 0.f;
    } else {
        int idx = (blk - PB_Z) * 256 + tid;
        if (idx < DCTN * DCTN) {
            int k = idx / DCTN, i = idx % DCTN;
            double w = (k == 0) ? sqrt(1.0 / DCTN) : sqrt(2.0 / DCTN);
            dct[idx] = (float)(w * cos(3.14159265358979323846 * (i + 0.5) * k / (double)DCTN));
        }
    }
}

// ---------------- NT MFMA GEMM, BK=64, global_load_lds staging, XOR-swizzled LDS ----------
// XCD-aware block mapping:
//   mode 0: mb = blockIdx.y, nb = blockIdx.x
//   mode 1: n-partitioned per XCD (stream = B): x=gx&7; s=gx>>3; mb=s%CNT; nb=x*Pc+s/CNT
//   mode 2: m-partitioned per XCD (stream = A): x=gx&7; s=gx>>3; nb=s%CNT; mb=x*Pc+s/CNT
template<int BM, int BN>
__global__ __launch_bounds__(256) void gemm2(
    const ushort* __restrict__ A, const ushort* __restrict__ Bt,
    const ushort* __restrict__ zpad,
    int M, int N, int K,
    int mode, int CNT, int Pc,
    int rpbA, long long sAw, long long sAr, long long sAbz,
    long long sBr, long long sBbz,
    float* __restrict__ C, ushort* __restrict__ C16,
    long long sCbz, long long sCm, long long sCn,
    int do_relu, const float* __restrict__ bias, int bias_mode,
    const float* __restrict__ bnTg, const float* __restrict__ bnTb,
    int do_tanh, const ushort* __restrict__ resid16, const float* __restrict__ resid32)
{
    constexpr int SM = BM / 32, SN = BN / 32;
    constexpr int RA = BM / 32, RB = BN / 32;     // staging rounds, 32 rows each
    __shared__ ushort As[BM * 64];
    __shared__ ushort Bs[BN * 64];

    int mb, nb;
    if (mode == 0) { mb = blockIdx.y; nb = blockIdx.x; }
    else {
        int gx = blockIdx.x;
        int x = gx & 7, s = gx >> 3;
        if (mode == 1) { mb = s % CNT; nb = x * Pc + s / CNT; }
        else           { nb = s % CNT; mb = x * Pc + s / CNT; }
    }
    const int m0 = mb * BM, n0 = nb * BN;
    if (m0 >= M || n0 >= N) return;          // block-uniform: safe before barriers

    const int tid = threadIdx.x;
    const int lane = tid & 63, w = tid >> 6;
    const int bz = blockIdx.z;
    const int wm = (w >> 1) * (BM / 2), wn = (w & 1) * (BN / 2);
    const int chunk = (lane & 7) ^ ((lane >> 3) & 7);

    const ushort* pA[RA]; int stA[RA];
    #pragma unroll
    for (int j = 0; j < RA; j++) {
        int m = m0 + j * 32 + w * 8 + (lane >> 3);
        bool v = m < M;
        long long off = v ? ((long long)(m / rpbA) * sAw + (long long)(m % rpbA) * sAr
                            + (long long)bz * sAbz) : 0;
        pA[j] = v ? (A + off + chunk * 8) : (zpad + chunk * 8);
        stA[j] = v ? 64 : 0;
    }
    const ushort* pB[RB]; int stB[RB];
    #pragma unroll
    for (int j = 0; j < RB; j++) {
        int n = n0 + j * 32 + w * 8 + (lane >> 3);
        bool v = n < N;
        long long off = v ? ((long long)n * sBr + (long long)bz * sBbz) : 0;
        pB[j] = v ? (Bt + off + chunk * 8) : (zpad + chunk * 8);
        stB[j] = v ? 64 : 0;
    }

    floatx4 acc[SM][SN];
    #pragma unroll
    for (int i = 0; i < SM; i++)
        #pragma unroll
        for (int j = 0; j < SN; j++)
            acc[i][j] = (floatx4){0.f, 0.f, 0.f, 0.f};

    for (int k0 = 0; k0 < K; k0 += 64) {
        #pragma unroll
        for (int j = 0; j < RA; j++)
            GLOAD_LDS(pA[j], &As[(j * 32 + w * 8) * 64]);
        #pragma unroll
        for (int j = 0; j < RB; j++)
            GLOAD_LDS(pB[j], &Bs[(j * 32 + w * 8) * 64]);
        __syncthreads();

        #pragma unroll
        for (int kk = 0; kk < 2; kk++) {
            short8 af[SM], bf[SN];
            #pragma unroll
            for (int sm = 0; sm < SM; sm++) {
                int lr = wm + sm * 16 + (lane & 15);
                int slot = ((lane >> 4) + kk * 4) ^ (lr & 7);
                af[sm] = *(const short8*)&As[lr * 64 + slot * 8];
            }
            #pragma unroll
            for (int sn = 0; sn < SN; sn++) {
                int lr = wn + sn * 16 + (lane & 15);
                int slot = ((lane >> 4) + kk * 4) ^ (lr & 7);
                bf[sn] = *(const short8*)&Bs[lr * 64 + slot * 8];
            }
            #pragma unroll
            for (int sm = 0; sm < SM; sm++)
                #pragma unroll
                for (int sn = 0; sn < SN; sn++)
                    acc[sm][sn] = __builtin_amdgcn_mfma_f32_16x16x32_bf16(af[sm], bf[sn], acc[sm][sn], 0, 0, 0);
        }
        __syncthreads();

        #pragma unroll
        for (int j = 0; j < RA; j++) pA[j] += stA[j];
        #pragma unroll
        for (int j = 0; j < RB; j++) pB[j] += stB[j];
    }

    // epilogue: D mapping col(n)=lane&15, row(m)=(lane>>4)*4+r
    const int lc = lane & 15;
    const int lr4 = (lane >> 4) << 2;
    #pragma unroll
    for (int sm = 0; sm < SM; sm++) {
        #pragma unroll
        for (int sn = 0; sn < SN; sn++) {
            int n = n0 + wn + sn * 16 + lc;
            if (n >= N) continue;
            int node = n % 136;
            int mbv = m0 + wm + sm * 16 + lr4;
            float vv[4];
            #pragma unroll
            for (int r = 0; r < 4; r++) {
                int m = mbv + r;
                float v = acc[sm][sn][r];
                if (do_relu) v = fmaxf(v, 0.f);
                if (bias) v += (bias_mode == 1) ? bias[m < M ? m : 0] : bias[n];
                if (bnTg) {
                    long long gi = (long long)(m < M ? m : 0) * 136 + node;
                    v = bnTg[gi] * (v * BN_SCALE) + bnTb[gi];
                }
                if (do_tanh) v = tanh_fast(v);
                long long addr = (long long)bz * sCbz + (long long)m * sCm + (long long)n * sCn;
                if (m < M) {
                    if (resid16) v += bf2f(resid16[addr]);
                    else if (resid32) v += resid32[addr];
                    if (C) C[addr] = v;
                    if (C16 && sCm != 1) C16[addr] = f2bf(v);
                }
                vv[r] = v;
            }
            if (C16 && sCm == 1 && mbv + 3 < M) {
                ushort4 pk;
                pk.x = f2bf(vv[0]); pk.y = f2bf(vv[1]); pk.z = f2bf(vv[2]); pk.w = f2bf(vv[3]);
                *(ushort4*)&C16[(long long)bz * sCbz + mbv + (long long)n * sCn] = pk;
            }
        }
    }
}

// ---------------- fused residual-GCN layer: mix (nodes) + W (channels), one block/batch ----
// z[c,n] = sum_m y[c,m] * att[n,m]   (stays in LDS, XOR-swizzled)
// out[c2,n] = tanh(bn(sum_c W[c2,c] * z[c,n] + bias[c2])) (+resid)
// Grid 256 (= 1 block/CU), 512 threads (8 waves). ONE __syncthreads total.
// Phase 1: wave w owns channel panel c in [w*64, w*64+64); y streams HBM->regs.
// Phase 2: wave w owns (c2 panel of 128) x (n-half); W streams L2->regs, z from LDS.
//   n-tile OWNERSHIP: half0 writes nt 0..3, half1 writes nt 4..8 — tile 4 is
//   computed by both halves but WRITTEN ONLY by half1 (in-place resid makes a
//   duplicate write a read-modify-write race — round-6 bug).
// LDS z layout: row n (stride 512 ushorts), 8-ushort chunks XOR-swizzled by (n&7).
__global__ __launch_bounds__(512, 2) void fused_layer(
    const ushort* __restrict__ Yin,   // feature-major [512][RP]
    const ushort* __restrict__ Att,   // [135][192]
    const ushort* __restrict__ Wt,    // [512][512], row c2, col c
    const ushort* __restrict__ zpad,
    const float* __restrict__ bias,   // [512] per c2
    const float* __restrict__ bnTg, const float* __restrict__ bnTb,  // gi = c2*136+n
    const ushort* __restrict__ resid16,   // nullable, layout = Yout
    ushort* __restrict__ Yout)        // feature-major [512][RP]
{
    extern __shared__ ushort zs[];    // 136 * 512 ushorts = 139264 B
    const int b = blockIdx.x;
    const int tid = threadIdx.x;
    const int lane = tid & 63, w = tid >> 6;
    const int ln = lane & 15;
    const int lk8 = (lane >> 4) * 8;
    const int lr4 = (lane >> 4) << 2;
    const long long ybase = (long long)b * 136;

    // ---------------- phase 1: mix into z LDS ----------------
    {
        const int cp = w * 64;
        const ushort* pb[9];
        #pragma unroll
        for (int nt = 0; nt < 9; nt++) {
            int n = nt * 16 + ln;
            pb[nt] = (n < 135) ? (Att + (long long)n * 192 + lk8) : (zpad + lk8);
        }
        const ushort* pa[4];
        #pragma unroll
        for (int sm = 0; sm < 4; sm++) {
            int c = cp + sm * 16 + ln;
            pa[sm] = Yin + (long long)c * RP + ybase + lk8;
        }
        floatx4 acc[4][9];
        #pragma unroll
        for (int i = 0; i < 4; i++)
            #pragma unroll
            for (int j = 0; j < 9; j++)
                acc[i][j] = (floatx4){0.f, 0.f, 0.f, 0.f};

        // K = 160 node-dim (m in [0,160); att zero for m >= 135)
        #pragma unroll
        for (int kc = 0; kc < 3; kc++) {
            #pragma unroll
            for (int kk = 0; kk < 2; kk++) {
                if (kc == 2 && kk == 1) continue;
                const int ko = kc * 64 + kk * 32;
                short8 af[4], bf[9];
                #pragma unroll
                for (int sm = 0; sm < 4; sm++)
                    af[sm] = *(const short8*)(pa[sm] + ko);
                #pragma unroll
                for (int nt = 0; nt < 9; nt++)
                    bf[nt] = *(const short8*)(pb[nt] + ko);
                #pragma unroll
                for (int sm = 0; sm < 4; sm++)
                    #pragma unroll
                    for (int nt = 0; nt < 9; nt++)
                        acc[sm][nt] = __builtin_amdgcn_mfma_f32_16x16x32_bf16(af[sm], bf[nt], acc[sm][nt], 0, 0, 0);
            }
        }
        // epilogue: lane holds col n = nt*16+ln, rows c = cp+sm*16+lr4+r
        #pragma unroll
        for (int sm = 0; sm < 4; sm++) {
            #pragma unroll
            for (int nt = 0; nt < 9; nt++) {
                int n = nt * 16 + ln;
                if (n >= 136) continue;
                int c = cp + sm * 16 + lr4;
                ushort4 pk;
                pk.x = f2bf(acc[sm][nt][0]);
                pk.y = f2bf(acc[sm][nt][1]);
                pk.z = f2bf(acc[sm][nt][2]);
                pk.w = f2bf(acc[sm][nt][3]);
                int chs = (c >> 3) ^ (n & 7);
                *(ushort4*)&zs[n * 512 + chs * 8 + (c & 7)] = pk;
            }
        }
    }
    __syncthreads();

    // ---------------- phase 2: W transform from z LDS ----------------
    {
        const int p = (w >> 1) * 128;             // c2 panel
        const int nt0 = (w & 1) ? 4 : 0;          // n-tiles computed: [0..4] / [4..8]
        // row pointers for weights
        const ushort* pw[8];
        #pragma unroll
        for (int sm = 0; sm < 8; sm++)
            pw[sm] = Wt + (long long)(p + sm * 16 + ln) * 512 + lk8;
        // z row bases
        int zrow[5], zx[5];
        #pragma unroll
        for (int j = 0; j < 5; j++) {
            int n = (nt0 + j) * 16 + ln;
            int nn = (n < 136) ? n : 0;
            zrow[j] = nn * 512;
            zx[j] = nn & 7;
        }
        floatx4 acc[8][5];
        #pragma unroll
        for (int i = 0; i < 8; i++)
            #pragma unroll
            for (int j = 0; j < 5; j++)
                acc[i][j] = (floatx4){0.f, 0.f, 0.f, 0.f};

        #pragma unroll
        for (int kc = 0; kc < 8; kc++) {
            #pragma unroll
            for (int kk = 0; kk < 2; kk++) {
                const int ko = kc * 64 + kk * 32;
                const int kchunk = kc * 8 + kk * 4 + (lane >> 4);
                short8 af[8], bf[5];
                #pragma unroll
                for (int sm = 0; sm < 8; sm++)
                    af[sm] = *(const short8*)(pw[sm] + ko);
                #pragma unroll
                for (int j = 0; j < 5; j++)
                    bf[j] = *(const short8*)&zs[zrow[j] + (kchunk ^ zx[j]) * 8];
                #pragma unroll
                for (int sm = 0; sm < 8; sm++)
                    #pragma unroll
                    for (int j = 0; j < 5; j++)
                        acc[sm][j] = __builtin_amdgcn_mfma_f32_16x16x32_bf16(af[sm], bf[j], acc[sm][j], 0, 0, 0);
            }
        }
        // epilogue — each (c2, n) written by exactly ONE wave:
        //   half0 (w&1==0) owns nt 0..3; half1 owns nt 4..8.
        #pragma unroll
        for (int sm = 0; sm < 8; sm++) {
            #pragma unroll
            for (int j = 0; j < 5; j++) {
                int nt = nt0 + j;
                if (nt == 4 && (w & 1) == 0) continue;   // race fix: tile 4 -> half1 only
                int n = nt * 16 + ln;
                if (n >= 136) continue;
                int c2 = p + sm * 16 + lr4;
                #pragma unroll
                for (int r = 0; r < 4; r++) {
                    int m = c2 + r;
                    float v = acc[sm][j][r];
                    v += bias[m];
                    long long gi = (long long)m * 136 + n;
                    v = bnTg[gi] * (v * BN_SCALE) + bnTb[gi];
                    v = tanh_fast(v);
                    long long addr = (long long)m * RP + ybase + n;
                    if (resid16) v += bf2f(resid16[addr]);
                    Yout[addr] = f2bf(v);
                }
            }
        }
    }
}

// ---------------- attention scores + normalize (wave-parallel) ----------------
__global__ __launch_bounds__(256) void att_k(const float* __restrict__ kf, const float* __restrict__ qf,
                                             float* __restrict__ att) {
    int b = blockIdx.x;
    int tid = threadIdx.x;
    int lane = tid & 63, w = tid >> 6;
    __shared__ float s[96];
    __shared__ float ssum;
    const float* qb = qf + b * DD + lane * 8;
    float4 q0 = *(const float4*)qb;
    float4 q1 = *(const float4*)(qb + 4);
    const float* kb = kf + (long long)b * VN * DD;
    for (int v = w; v < VN; v += 4) {
        const float* kr = kb + v * DD + lane * 8;
        float4 k0 = *(const float4*)kr;
        float4 k1 = *(const float4*)(kr + 4);
        float p = q0.x * k0.x + q0.y * k0.y + q0.z * k0.z + q0.w * k0.w
                + q1.x * k1.x + q1.y * k1.y + q1.z * k1.z + q1.w * k1.w;
        #pragma unroll
        for (int off = 32; off; off >>= 1) p += __shfl_xor(p, off);
        if (lane == 0) s[v] = p + 1e-15f;
    }
    __syncthreads();
    if (tid < 64) {
        float p2 = (tid < VN ? s[tid] : 0.f) + ((tid + 64) < VN ? s[tid + 64] : 0.f);
        #pragma unroll
        for (int off = 32; off; off >>= 1) p2 += __shfl_xor(p2, off);
        if (tid == 0) ssum = p2;
    }
    __syncthreads();
    float inv = 1.f / ssum;
    for (int v = tid; v < VN; v += 256) att[b * VN + v] = s[v] * inv;
}

// ---------------- w34[b,t,f] = sum_v att[b,v] * poses[b,v+t,f] ----------------
__global__ void weighted_k(const float* __restrict__ poses, const float* __restrict__ att,
                           float* __restrict__ w34) {
    int t = blockIdx.x;
    int b = blockIdx.y;
    int f = threadIdx.x;
    if (f >= NF) return;
    const float* pb = poses + (long long)b * POSE_ROWS * NF + t * NF + f;
    const float* ab = att + b * VN;
    float acc = 0.f;
    for (int v = 0; v < VN; v++) acc += ab[v] * pb[v * NF];
    w34[(long long)b * DCTN * NF + t * NF + f] = acc;
}

// ---------------- x = concat(dct_in, dct_att); node-major f32 + feature-major bf16 ----
__global__ void build_x(const float* __restrict__ poses, const float* __restrict__ w34,
                        const float* __restrict__ dctm, float* __restrict__ x32,
                        ushort* __restrict__ xT16) {
    int idx = blockIdx.x * 256 + threadIdx.x;
    if (idx >= BATCH * NF * 68) return;
    int kk = idx % 68;
    int f = (idx / 68) % NF;
    int b = idx / (68 * NF);
    float acc = 0.f;
    if (kk < DCTN) {
        const float* pb = poses + (long long)b * POSE_ROWS * NF;
        #pragma unroll
        for (int t = 0; t < DCTN; t++) {
            int row = (t < KQ) ? (INN - KQ + t) : (INN - 1);
            acc += dctm[kk * DCTN + t] * pb[row * NF + f];
        }
    } else {
        int k2 = kk - DCTN;
        const float* wb = w34 + (long long)b * DCTN * NF + f;
        #pragma unroll
        for (int t = 0; t < DCTN; t++) acc += dctm[k2 * DCTN + t] * wb[t * NF];
    }
    long long R = (long long)b * NODEP + f;
    x32[R * 68 + kk] = acc;
    xT16[(long long)kk * RP + R] = f2bf(acc);
}

// ---------------- preds[b,t,f] = sum_k dct[k][10+t] * h32[(b*136+f)*68+k] ----------------
__global__ void idct_out(const float* __restrict__ h32, const float* __restrict__ dctm,
                         float* __restrict__ out) {
    int idx = blockIdx.x * 256 + threadIdx.x;
    if (idx >= BATCH * OUTN * NF) return;
    int f = idx % NF;
    int t = (idx / NF) % OUTN;
    int b = idx / (NF * OUTN);
    const float* yr = h32 + ((long long)b * NODEP + f) * 68;
    float acc = 0.f;
    #pragma unroll
    for (int k = 0; k < DCTN; k++) acc += dctm[k * DCTN + (KQ + t)] * yr[k];
    out[idx] = acc;
}

// ---------------- host ----------------
extern "C" void kernel_launch(void* const* d_in, const int* in_sizes, int n_in,
                              void* d_out, int out_size, void* d_ws, size_t ws_size,
                              hipStream_t stream) {
    const float* poses   = (const float*)d_in[0];
    const float* qw1     = (const float*)d_in[1];
    const float* qw2     = (const float*)d_in[2];
    const float* kw1     = (const float*)d_in[3];
    const float* kw2     = (const float*)d_in[4];
    const float* gc1_att = (const float*)d_in[5];
    const float* gc1_w   = (const float*)d_in[6];
    const float* gc1_b   = (const float*)d_in[7];
    const float* bn1_g   = (const float*)d_in[8];
    const float* bn1_b   = (const float*)d_in[9];
    const float* gcb_att = (const float*)d_in[10];
    const float* gcb_w   = (const float*)d_in[11];
    const float* gcb_b   = (const float*)d_in[12];
    const float* gcb_g   = (const float*)d_in[13];
    const float* gcb_beta= (const float*)d_in[14];
    const float* gc7_att = (const float*)d_in[15];
    const float* gc7_w   = (const float*)d_in[16];
    const float* gc7_b   = (const float*)d_in[17];
    float* out = (float*)d_out;
    float* w = (float*)d_ws;

    // ---- workspace layout (f32 units) ----
    float* dct   = w;                      // 1156 -> pad 1280
    float* att   = w + 1280;               // -> 23808
    float* w34   = w + 23808;              // -> 1198848
    float* x32   = w + 1198848;            // RP*68 -> 3566336
    float* h32   = w + 3566336;            // RP*68 -> 5933824
    float* qf    = w + 5933824;            // -> 6064896
    ushort* su   = (ushort*)(w + 6064896); // bf16 weight region
    ushort* WT1    = su;                   // 512*128   = 65536
    ushort* WTb    = su + 65536;           // 4*512*512 = 1048576
    ushort* WT7    = su + 1114112;         // 68*512    = 34816
    ushort* A16_1  = su + 1148928;         // 135*192   = 25920
    ushort* A16_B  = su + 1174848;         // 540*192   = 103680
    ushort* A16_7  = su + 1278528;         // 25920
    float* bnT   = w + 6717120;            // 10 * 69632 -> 7413440
    float* kf    = w + 7413440;            // 256*87*512 -> 18816704
    ushort* R2   = (ushort*)(w + 18816704);
    ushort* yT16  = R2;
    ushort* r1k16 = R2;                    // phase-A alias
    ushort* r1q16 = R2 + 11927552;
    ushort* R3   = (ushort*)(w + 27729600);
    ushort* hT16  = R3;
    ushort* pb16  = R3;                    // phase-A alias
    ushort* Wt1k  = R3 + 5013504;
    ushort* Wt1q  = R3 + 5439488;
    ushort* Wt2k  = R3 + 5865472;
    ushort* Wt2q  = R3 + 7176192;
    ushort* R4   = (ushort*)(w + 36642496);
    ushort* zN16  = R4;
    ushort* xT16  = R4;                    // alias (dead before zN16 written)
    ushort* z116  = R4 + 2367488;          // RP*80
    float* zpadf = w + 45555392;           // 128 f zero page
    const ushort* zpad = (const ushort*)zpadf;

    const int INF_RPB = 1 << 30;

    // allow 139 KB dynamic LDS for fused_layer (graph-safe: not a stream op)
    static int lds_set = 0;
    if (!lds_set) {
        hipFuncSetAttribute((const void*)fused_layer,
                            hipFuncAttributeMaxDynamicSharedMemorySize, 139264);
        lds_set = 1;
    }

    // ---- fused prep (one dispatch) ----
    prep_all<<<PB_DCT, 256, 0, stream>>>(
        poses, pb16, kw1, qw1, Wt1k, Wt1q, kw2, qw2, Wt2k, Wt2q,
        gc1_w, WT1, gcb_w, WTb, gc7_w, WT7,
        gc1_att, A16_1, gcb_att, A16_B, gc7_att, A16_7,
        bn1_g, bn1_b, gcb_g, gcb_beta, bnT, zpadf, dct);

    // ---- conv stack ----
    // conv1k: BM=128,BN=64; A-stream m-partitioned per XCD (mode 2): 182 m-blocks, Pc=23
    gemm2<128,64><<<dim3(1472, 1, 1), 256, 0, stream>>>(pb16, Wt1k, zpad, 23296, 512, 832,
        2, 8, 23, 91, 19584LL, 136LL, 0LL, 832LL, 0LL,
        (float*)nullptr, r1k16, 0LL, 512LL, 1LL, 1, nullptr, 0, nullptr, nullptr, 0, nullptr, nullptr);
    gemm2<128,128><<<dim3(4, 10, 1), 256, 0, stream>>>(pb16 + 110*136, Wt1q, zpad, 1280, 512, 832,
        0, 0, 0, 5, 19584LL, 136LL, 0LL, 832LL, 0LL,
        (float*)nullptr, r1q16, 0LL, 512LL, 1LL, 1, nullptr, 0, nullptr, nullptr, 0, nullptr, nullptr);
    // conv2k: BM=128,BN=64; mode 2: 174 m-blocks, Pc=22
    gemm2<128,64><<<dim3(1408, 1, 1), 256, 0, stream>>>(r1k16, Wt2k, zpad, 22272, 512, 2560,
        2, 8, 22, 87, 46592LL, 512LL, 0LL, 2560LL, 0LL,
        kf, (ushort*)nullptr, 0LL, 512LL, 1LL, 1, nullptr, 0, nullptr, nullptr, 0, nullptr, nullptr);
    gemm2<64,64><<<dim3(8, 4, 1), 256, 0, stream>>>(r1q16, Wt2q, zpad, 256, 512, 2560,
        0, 0, 0, INF_RPB, 0LL, 2560LL, 0LL, 2560LL, 0LL,
        qf, (ushort*)nullptr, 0LL, 512LL, 1LL, 1, nullptr, 0, nullptr, nullptr, 0, nullptr, nullptr);

    // ---- attention + x ----
    att_k<<<BATCH, 256, 0, stream>>>(kf, qf, att);
    weighted_k<<<dim3(DCTN, BATCH), 192, 0, stream>>>(poses, att, w34);
    build_x<<<(BATCH * NF * 68 + 255) / 256, 256, 0, stream>>>(poses, w34, dct, x32, xT16);

    // ---- gc1: mix then W(68->512) ----
    gemm2<64,64><<<dim3(3, 2, BATCH), 256, 0, stream>>>(xT16, A16_1, zpad, 68, 135, 192,
        0, 0, 0, INF_RPB, 0LL, (long long)RP, 136LL, 192LL, 0LL,
        (float*)nullptr, z116, 10880LL, 1LL, 80LL, 0, nullptr, 0, nullptr, nullptr, 0, nullptr, nullptr);
    // gc1 W: BM=128,BN=64; B-stream n-partitioned per XCD (mode 1): MBc=4, Pc=68
    gemm2<128,64><<<dim3(2176, 1, 1), 256, 0, stream>>>(WT1, z116, zpad, 512, RP, 128,
        1, 4, 68, INF_RPB, 0LL, 128LL, 0LL, 80LL, 0LL,
        (float*)nullptr, yT16, 0LL, (long long)RP, 1LL, 0, gc1_b, 1, bnT, bnT + 69632, 1, nullptr, nullptr);

    // ---- residual GCN blocks: one fused dispatch per layer ----
    for (int L = 0; L < 4; L++) {
        const ushort* min = (L & 1) ? hT16 : yT16;
        ushort* mout = (L & 1) ? yT16 : hT16;
        fused_layer<<<dim3(BATCH, 1, 1), 512, 139264, stream>>>(
            min, A16_B + L * 25920, WTb + L * 262144, zpad,
            gcb_b + L * 512, bnT + (1 + L) * 139264, bnT + (1 + L) * 139264 + 69632,
            (L & 1) ? yT16 : (const ushort*)nullptr, mout);
    }

    // ---- gc7: mix then W(512->68) + bias + x residual ----
    gemm2<64,64><<<dim3(3, 8, BATCH), 256, 0, stream>>>(yT16, A16_7, zpad, 512, 135, 192,
        0, 0, 0, INF_RPB, 0LL, (long long)RP, 136LL, 192LL, 0LL,
        (float*)nullptr, zN16, 69632LL, 1LL, 512LL, 0, nullptr, 0, nullptr, nullptr, 0, nullptr, nullptr);
    // gc7 W: BM=64,BN=64; A-stream m-partitioned per XCD (mode 2): NBc=2, Pc=68
    gemm2<64,64><<<dim3(1088, 1, 1), 256, 0, stream>>>(zN16, WT7, zpad, RP, 68, 512,
        2, 2, 68, INF_RPB, 0LL, 512LL, 0LL, 512LL, 0LL,
        h32, (ushort*)nullptr, 0LL, 68LL, 1LL, 0, gc7_b, 2, nullptr, nullptr, 0, nullptr, x32);

    idct_out<<<(BATCH * OUTN * NF + 255) / 256, 256, 0, stream>>>(h32, dct, out);
}

// Round 8
// 895.685 us; speedup vs baseline: 1.6708x; 1.1375x over previous
//
#include <hip/hip_runtime.h>
#include <math.h>

// ---------------- problem constants ----------------
#define POSE_ROWS 144
#define NF 135
#define DD 512
#define KQ 10
#define DCTN 34
#define INN 120
#define OUTN 24
#define VN 87
#define BATCH 256
#define RP 34816              // padded row dim: 256 * 136
#define NODEP 136
#define BN_SCALE 0.9999950000374997f

typedef __attribute__((ext_vector_type(8))) short short8;
typedef __attribute__((ext_vector_type(4))) float floatx4;

static __device__ __forceinline__ ushort f2bf(float f) {
    unsigned u = __builtin_bit_cast(unsigned, f);
    u = (u + 0x7FFFu + ((u >> 16) & 1u)) >> 16;
    return (ushort)u;
}
static __device__ __forceinline__ float bf2f(ushort s) {
    return __builtin_bit_cast(float, (unsigned)s << 16);
}
// fast tanh via exp2
static __device__ __forceinline__ float tanh_fast(float x) {
    float ax = __builtin_fabsf(x);
    float e = __builtin_amdgcn_exp2f(ax * -2.885390081777927f);   // e^{-2ax}
    float t = (1.f - e) * __builtin_amdgcn_rcpf(1.f + e);
    return __builtin_copysignf(t, x);
}

#define GLOAD_LDS(gp, lp) __builtin_amdgcn_global_load_lds( \
    (const __attribute__((address_space(1))) unsigned int*)(const void*)(gp), \
    (__attribute__((address_space(3))) unsigned int*)(void*)(lp), 16, 0, 0)

// ---------------- fused prep kernel (all weight repacks / converts in ONE dispatch) ----
#define PB_POSES 19584
#define PB_K1B   22912
#define PB_K2B   33152
#define PB_WT1   33408
#define PB_WTB   37504
#define PB_WT7   37640
#define PB_A1    37742
#define PB_AB    38147
#define PB_A7    38249
#define PB_BN    39609
#define PB_Z     39610
#define PB_DCT   39615

__global__ __launch_bounds__(256) void prep_all(
    const float* __restrict__ poses, ushort* __restrict__ pb16,
    const float* __restrict__ kw1, const float* __restrict__ qw1,
    ushort* __restrict__ Wt1k, ushort* __restrict__ Wt1q,
    const float* __restrict__ kw2, const float* __restrict__ qw2,
    ushort* __restrict__ Wt2k, ushort* __restrict__ Wt2q,
    const float* __restrict__ gc1_w, ushort* __restrict__ WT1,
    const float* __restrict__ gcb_w, ushort* __restrict__ WTb,
    const float* __restrict__ gc7_w, ushort* __restrict__ WT7,
    const float* __restrict__ gc1_att, ushort* __restrict__ A16_1,
    const float* __restrict__ gcb_att, ushort* __restrict__ A16_B,
    const float* __restrict__ gc7_att, ushort* __restrict__ A16_7,
    const float* __restrict__ bn1_g, const float* __restrict__ bn1_b,
    const float* __restrict__ gcb_g, const float* __restrict__ gcb_beta,
    float* __restrict__ bnT, float* __restrict__ zpadf, float* __restrict__ dct)
{
    const int blk = blockIdx.x;
    const int tid = threadIdx.x;
    if (blk < PB_POSES) {
        int idx = blk * 256 + tid;
        int i = idx % NODEP;
        int row = (idx / NODEP) % POSE_ROWS;
        int b = idx / (NODEP * POSE_ROWS);
        float v = (i < NF) ? poses[((long long)b * POSE_ROWS + row) * NF + i] * 1e-3f : 0.f;
        pb16[idx] = f2bf(v);
    } else if (blk < PB_K1B) {
        int wi = blk - PB_POSES;
        const float* src = (wi < 1664) ? kw1 : qw1;
        ushort* dst = (wi < 1664) ? Wt1k : Wt1q;
        int idx = (wi % 1664) * 256 + tid;
        int n = idx / 832, k = idx % 832;
        int h = k / 136, i = k % 136;
        float v = (i < 135 && h < 6) ? src[((long long)n * 135 + i) * 6 + h] : 0.f;
        dst[idx] = f2bf(v);
    } else if (blk < PB_K2B) {
        int wi = blk - PB_K1B;
        const float* src = (wi < 5120) ? kw2 : qw2;
        ushort* dst = (wi < 5120) ? Wt2k : Wt2q;
        int idx = (wi % 5120) * 256 + tid;
        int n = idx / 2560, k = idx % 2560;
        int h = k / 512, i = k % 512;
        dst[idx] = f2bf(src[((long long)n * 512 + i) * 5 + h]);
    } else if (blk < PB_WT1) {
        int idx = (blk - PB_K2B) * 256 + tid;
        int n = idx / 128, k = idx % 128;
        WT1[idx] = f2bf((k < 68) ? gc1_w[(long long)k * 512 + n] : 0.f);
    } else if (blk < PB_WTB) {
        int g = (blk - PB_WT1) * 256 + tid;
        int L = g >> 18, idx = g & 262143;
        int n = idx / 512, k = idx % 512;
        WTb[g] = f2bf(gcb_w[(long long)L * 262144 + (long long)k * 512 + n]);
    } else if (blk < PB_WT7) {
        int idx = (blk - PB_WTB) * 256 + tid;
        int n = idx / 512, k = idx % 512;
        WT7[idx] = f2bf(gc7_w[(long long)k * 68 + n]);
    } else if (blk < PB_A1) {
        int idx = (blk - PB_WT7) * 256 + tid;
        if (idx < 135 * 192) {
            int r = idx / 192, c = idx % 192;
            A16_1[idx] = f2bf(c < 135 ? gc1_att[r * 135 + c] : 0.f);
        }
    } else if (blk < PB_AB) {
        int idx = (blk - PB_A1) * 256 + tid;
        int r = idx / 192, c = idx % 192;
        A16_B[idx] = f2bf(c < 135 ? gcb_att[r * 135 + c] : 0.f);
    } else if (blk < PB_A7) {
        int idx = (blk - PB_AB) * 256 + tid;
        if (idx < 135 * 192) {
            int r = idx / 192, c = idx % 192;
            A16_7[idx] = f2bf(c < 135 ? gc7_att[r * 135 + c] : 0.f);
        }
    } else if (blk < PB_BN) {
        int g = (blk - PB_A7) * 256 + tid;
        int p = g / 69632, idx = g % 69632;
        int node = idx % 136, m = idx / 136;
        const float* gs = (p == 0) ? bn1_g : (gcb_g + (p - 1) * 69120);
        const float* bs = (p == 0) ? bn1_b : (gcb_beta + (p - 1) * 69120);
        float* gt = bnT + (long long)p * 139264;
        float* bt = gt + 69632;
        gt[idx] = (node < 135) ? gs[node * 512 + m] : 0.f;
        bt[idx] = (node < 135) ? bs[node * 512 + m] : 0.f;
    } else if (blk < PB_Z) {
        if (tid < 128) zpadf[tid] = 0.f;
    } else {
        int idx = (blk - PB_Z) * 256 + tid;
        if (idx < DCTN * DCTN) {
            int k = idx / DCTN, i = idx % DCTN;
            double w = (k == 0) ? sqrt(1.0 / DCTN) : sqrt(2.0 / DCTN);
            dct[idx] = (float)(w * cos(3.14159265358979323846 * (i + 0.5) * k / (double)DCTN));
        }
    }
}

// ---------------- NT MFMA GEMM, BK=64, global_load_lds staging, XOR-swizzled LDS ----------
// XCD-aware block mapping:
//   mode 0: mb = blockIdx.y, nb = blockIdx.x
//   mode 1: n-partitioned per XCD (stream = B): x=gx&7; s=gx>>3; mb=s%CNT; nb=x*Pc+s/CNT
//   mode 2: m-partitioned per XCD (stream = A): x=gx&7; s=gx>>3; nb=s%CNT; mb=x*Pc+s/CNT
template<int BM, int BN>
__global__ __launch_bounds__(256) void gemm2(
    const ushort* __restrict__ A, const ushort* __restrict__ Bt,
    const ushort* __restrict__ zpad,
    int M, int N, int K,
    int mode, int CNT, int Pc,
    int rpbA, long long sAw, long long sAr, long long sAbz,
    long long sBr, long long sBbz,
    float* __restrict__ C, ushort* __restrict__ C16,
    long long sCbz, long long sCm, long long sCn,
    int do_relu, const float* __restrict__ bias, int bias_mode,
    const float* __restrict__ bnTg, const float* __restrict__ bnTb,
    int do_tanh, const ushort* __restrict__ resid16, const float* __restrict__ resid32)
{
    constexpr int SM = BM / 32, SN = BN / 32;
    constexpr int RA = BM / 32, RB = BN / 32;     // staging rounds, 32 rows each
    __shared__ ushort As[BM * 64];
    __shared__ ushort Bs[BN * 64];

    int mb, nb;
    if (mode == 0) { mb = blockIdx.y; nb = blockIdx.x; }
    else {
        int gx = blockIdx.x;
        int x = gx & 7, s = gx >> 3;
        if (mode == 1) { mb = s % CNT; nb = x * Pc + s / CNT; }
        else           { nb = s % CNT; mb = x * Pc + s / CNT; }
    }
    const int m0 = mb * BM, n0 = nb * BN;
    if (m0 >= M || n0 >= N) return;          // block-uniform: safe before barriers

    const int tid = threadIdx.x;
    const int lane = tid & 63, w = tid >> 6;
    const int bz = blockIdx.z;
    const int wm = (w >> 1) * (BM / 2), wn = (w & 1) * (BN / 2);
    const int chunk = (lane & 7) ^ ((lane >> 3) & 7);

    const ushort* pA[RA]; int stA[RA];
    #pragma unroll
    for (int j = 0; j < RA; j++) {
        int m = m0 + j * 32 + w * 8 + (lane >> 3);
        bool v = m < M;
        long long off = v ? ((long long)(m / rpbA) * sAw + (long long)(m % rpbA) * sAr
                            + (long long)bz * sAbz) : 0;
        pA[j] = v ? (A + off + chunk * 8) : (zpad + chunk * 8);
        stA[j] = v ? 64 : 0;
    }
    const ushort* pB[RB]; int stB[RB];
    #pragma unroll
    for (int j = 0; j < RB; j++) {
        int n = n0 + j * 32 + w * 8 + (lane >> 3);
        bool v = n < N;
        long long off = v ? ((long long)n * sBr + (long long)bz * sBbz) : 0;
        pB[j] = v ? (Bt + off + chunk * 8) : (zpad + chunk * 8);
        stB[j] = v ? 64 : 0;
    }

    floatx4 acc[SM][SN];
    #pragma unroll
    for (int i = 0; i < SM; i++)
        #pragma unroll
        for (int j = 0; j < SN; j++)
            acc[i][j] = (floatx4){0.f, 0.f, 0.f, 0.f};

    for (int k0 = 0; k0 < K; k0 += 64) {
        #pragma unroll
        for (int j = 0; j < RA; j++)
            GLOAD_LDS(pA[j], &As[(j * 32 + w * 8) * 64]);
        #pragma unroll
        for (int j = 0; j < RB; j++)
            GLOAD_LDS(pB[j], &Bs[(j * 32 + w * 8) * 64]);
        __syncthreads();

        #pragma unroll
        for (int kk = 0; kk < 2; kk++) {
            short8 af[SM], bf[SN];
            #pragma unroll
            for (int sm = 0; sm < SM; sm++) {
                int lr = wm + sm * 16 + (lane & 15);
                int slot = ((lane >> 4) + kk * 4) ^ (lr & 7);
                af[sm] = *(const short8*)&As[lr * 64 + slot * 8];
            }
            #pragma unroll
            for (int sn = 0; sn < SN; sn++) {
                int lr = wn + sn * 16 + (lane & 15);
                int slot = ((lane >> 4) + kk * 4) ^ (lr & 7);
                bf[sn] = *(const short8*)&Bs[lr * 64 + slot * 8];
            }
            #pragma unroll
            for (int sm = 0; sm < SM; sm++)
                #pragma unroll
                for (int sn = 0; sn < SN; sn++)
                    acc[sm][sn] = __builtin_amdgcn_mfma_f32_16x16x32_bf16(af[sm], bf[sn], acc[sm][sn], 0, 0, 0);
        }
        __syncthreads();

        #pragma unroll
        for (int j = 0; j < RA; j++) pA[j] += stA[j];
        #pragma unroll
        for (int j = 0; j < RB; j++) pB[j] += stB[j];
    }

    // epilogue: D mapping col(n)=lane&15, row(m)=(lane>>4)*4+r
    const int lc = lane & 15;
    const int lr4 = (lane >> 4) << 2;
    #pragma unroll
    for (int sm = 0; sm < SM; sm++) {
        #pragma unroll
        for (int sn = 0; sn < SN; sn++) {
            int n = n0 + wn + sn * 16 + lc;
            if (n >= N) continue;
            int node = n % 136;
            int mbv = m0 + wm + sm * 16 + lr4;
            float vv[4];
            #pragma unroll
            for (int r = 0; r < 4; r++) {
                int m = mbv + r;
                float v = acc[sm][sn][r];
                if (do_relu) v = fmaxf(v, 0.f);
                if (bias) v += (bias_mode == 1) ? bias[m < M ? m : 0] : bias[n];
                if (bnTg) {
                    long long gi = (long long)(m < M ? m : 0) * 136 + node;
                    v = bnTg[gi] * (v * BN_SCALE) + bnTb[gi];
                }
                if (do_tanh) v = tanh_fast(v);
                long long addr = (long long)bz * sCbz + (long long)m * sCm + (long long)n * sCn;
                if (m < M) {
                    if (resid16) v += bf2f(resid16[addr]);
                    else if (resid32) v += resid32[addr];
                    if (C) C[addr] = v;
                    if (C16 && sCm != 1) C16[addr] = f2bf(v);
                }
                vv[r] = v;
            }
            if (C16 && sCm == 1 && mbv + 3 < M) {
                ushort4 pk;
                pk.x = f2bf(vv[0]); pk.y = f2bf(vv[1]); pk.z = f2bf(vv[2]); pk.w = f2bf(vv[3]);
                *(ushort4*)&C16[(long long)bz * sCbz + mbv + (long long)n * sCn] = pk;
            }
        }
    }
}

// ---------------- fused residual-GCN layer: mix (nodes) + W (channels), one block/batch ----
// z[c,n] = sum_m y[c,m] * att[n,m]   (stays in LDS, XOR-swizzled)
// out[c2,n] = tanh(bn(sum_c W[c2,c] * z[c,n] + bias[c2])) (+resid)
// Grid 256 (= 1 block/CU), 512 threads (8 waves). ONE __syncthreads total.
// BOTH phases: wave w owns a 64-channel panel (cp = w*64) x ALL 9 n-tiles.
//   -> acc[4][9] = 144 VGPR; per-wave output rows disjoint -> no write races,
//      in-place residual safe. JIT bf loads keep live ranges small.
// ROUND-8 FIX: round 7 had __launch_bounds__(512,2) = 128-VGPR cap while acc
// alone needs 144+ -> massive scratch spill (VGPR_Count=128, FETCH/WRITE
// inflated ~35MB by spill traffic, MfmaUtil 8%). Now: no min-waves bound
// (256-VGPR budget; occupancy is LDS-bound at 1 block/CU regardless).
// LDS z layout: row n (stride 512 ushorts), 8-ushort chunks XOR-swizzled by (n&7).
__global__ __launch_bounds__(512) void fused_layer(
    const ushort* __restrict__ Yin,   // feature-major [512][RP]
    const ushort* __restrict__ Att,   // [135][192]
    const ushort* __restrict__ Wt,    // [512][512], row c2, col c
    const ushort* __restrict__ zpad,
    const float* __restrict__ bias,   // [512] per c2
    const float* __restrict__ bnTg, const float* __restrict__ bnTb,  // gi = c2*136+n
    const ushort* __restrict__ resid16,   // nullable, layout = Yout
    ushort* __restrict__ Yout)        // feature-major [512][RP]
{
    extern __shared__ ushort zs[];    // 136 * 512 ushorts = 139264 B
    const int b = blockIdx.x;
    const int tid = threadIdx.x;
    const int lane = tid & 63, w = tid >> 6;
    const int ln = lane & 15;
    const int lk8 = (lane >> 4) * 8;
    const int lr4 = (lane >> 4) << 2;
    const long long ybase = (long long)b * 136;
    const int cp = w * 64;            // this wave's 64-channel panel (both phases)

    // ---------------- phase 1: mix into z LDS ----------------
    {
        const ushort* pb[9];
        #pragma unroll
        for (int nt = 0; nt < 9; nt++) {
            int n = nt * 16 + ln;
            pb[nt] = (n < 135) ? (Att + (long long)n * 192 + lk8) : (zpad + lk8);
        }
        const ushort* pa[4];
        #pragma unroll
        for (int sm = 0; sm < 4; sm++) {
            int c = cp + sm * 16 + ln;
            pa[sm] = Yin + (long long)c * RP + ybase + lk8;
        }
        floatx4 acc[4][9];
        #pragma unroll
        for (int i = 0; i < 4; i++)
            #pragma unroll
            for (int j = 0; j < 9; j++)
                acc[i][j] = (floatx4){0.f, 0.f, 0.f, 0.f};

        // K = 160 node-dim, 5 steps of 32 (att zero for m >= 135)
        #pragma unroll
        for (int ks = 0; ks < 5; ks++) {
            const int ko = ks * 32;
            short8 af[4];
            #pragma unroll
            for (int sm = 0; sm < 4; sm++)
                af[sm] = *(const short8*)(pa[sm] + ko);
            #pragma unroll
            for (int nt = 0; nt < 9; nt++) {
                short8 bfv = *(const short8*)(pb[nt] + ko);   // JIT: 1 live bf
                #pragma unroll
                for (int sm = 0; sm < 4; sm++)
                    acc[sm][nt] = __builtin_amdgcn_mfma_f32_16x16x32_bf16(af[sm], bfv, acc[sm][nt], 0, 0, 0);
            }
        }
        // epilogue: lane holds col n = nt*16+ln, rows c = cp+sm*16+lr4+r
        #pragma unroll
        for (int sm = 0; sm < 4; sm++) {
            #pragma unroll
            for (int nt = 0; nt < 9; nt++) {
                int n = nt * 16 + ln;
                if (n >= 136) continue;
                int c = cp + sm * 16 + lr4;
                ushort4 pk;
                pk.x = f2bf(acc[sm][nt][0]);
                pk.y = f2bf(acc[sm][nt][1]);
                pk.z = f2bf(acc[sm][nt][2]);
                pk.w = f2bf(acc[sm][nt][3]);
                int chs = (c >> 3) ^ (n & 7);
                *(ushort4*)&zs[n * 512 + chs * 8 + (c & 7)] = pk;
            }
        }
    }
    __syncthreads();

    // ---------------- phase 2: W transform from z LDS ----------------
    {
        const ushort* pw[4];
        #pragma unroll
        for (int sm = 0; sm < 4; sm++)
            pw[sm] = Wt + (long long)(cp + sm * 16 + ln) * 512 + lk8;
        int zrow[9], zx[9];
        #pragma unroll
        for (int nt = 0; nt < 9; nt++) {
            int n = nt * 16 + ln;
            int nn = (n < 136) ? n : 0;
            zrow[nt] = nn * 512;
            zx[nt] = nn & 7;
        }
        floatx4 acc[4][9];
        #pragma unroll
        for (int i = 0; i < 4; i++)
            #pragma unroll
            for (int j = 0; j < 9; j++)
                acc[i][j] = (floatx4){0.f, 0.f, 0.f, 0.f};

        // K = 512 channel-dim, 16 steps of 32
        #pragma unroll
        for (int ks = 0; ks < 16; ks++) {
            const int ko = ks * 32;
            const int kchunk = ks * 4 + (lane >> 4);
            short8 af[4];
            #pragma unroll
            for (int sm = 0; sm < 4; sm++)
                af[sm] = *(const short8*)(pw[sm] + ko);
            #pragma unroll
            for (int nt = 0; nt < 9; nt++) {
                short8 bfv = *(const short8*)&zs[zrow[nt] + (kchunk ^ zx[nt]) * 8];  // JIT
                #pragma unroll
                for (int sm = 0; sm < 4; sm++)
                    acc[sm][nt] = __builtin_amdgcn_mfma_f32_16x16x32_bf16(af[sm], bfv, acc[sm][nt], 0, 0, 0);
            }
        }
        // epilogue — wave's c2 rows are disjoint (cp panel): no duplicate writes
        #pragma unroll
        for (int sm = 0; sm < 4; sm++) {
            #pragma unroll
            for (int nt = 0; nt < 9; nt++) {
                int n = nt * 16 + ln;
                if (n >= 136) continue;
                int c2 = cp + sm * 16 + lr4;
                #pragma unroll
                for (int r = 0; r < 4; r++) {
                    int m = c2 + r;
                    float v = acc[sm][nt][r];
                    v += bias[m];
                    long long gi = (long long)m * 136 + n;
                    v = bnTg[gi] * (v * BN_SCALE) + bnTb[gi];
                    v = tanh_fast(v);
                    long long addr = (long long)m * RP + ybase + n;
                    if (resid16) v += bf2f(resid16[addr]);
                    Yout[addr] = f2bf(v);
                }
            }
        }
    }
}

// ---------------- attention scores + normalize (wave-parallel) ----------------
__global__ __launch_bounds__(256) void att_k(const float* __restrict__ kf, const float* __restrict__ qf,
                                             float* __restrict__ att) {
    int b = blockIdx.x;
    int tid = threadIdx.x;
    int lane = tid & 63, w = tid >> 6;
    __shared__ float s[96];
    __shared__ float ssum;
    const float* qb = qf + b * DD + lane * 8;
    float4 q0 = *(const float4*)qb;
    float4 q1 = *(const float4*)(qb + 4);
    const float* kb = kf + (long long)b * VN * DD;
    for (int v = w; v < VN; v += 4) {
        const float* kr = kb + v * DD + lane * 8;
        float4 k0 = *(const float4*)kr;
        float4 k1 = *(const float4*)(kr + 4);
        float p = q0.x * k0.x + q0.y * k0.y + q0.z * k0.z + q0.w * k0.w
                + q1.x * k1.x + q1.y * k1.y + q1.z * k1.z + q1.w * k1.w;
        #pragma unroll
        for (int off = 32; off; off >>= 1) p += __shfl_xor(p, off);
        if (lane == 0) s[v] = p + 1e-15f;
    }
    __syncthreads();
    if (tid < 64) {
        float p2 = (tid < VN ? s[tid] : 0.f) + ((tid + 64) < VN ? s[tid + 64] : 0.f);
        #pragma unroll
        for (int off = 32; off; off >>= 1) p2 += __shfl_xor(p2, off);
        if (tid == 0) ssum = p2;
    }
    __syncthreads();
    float inv = 1.f / ssum;
    for (int v = tid; v < VN; v += 256) att[b * VN + v] = s[v] * inv;
}

// ---------------- w34[b,t,f] = sum_v att[b,v] * poses[b,v+t,f] ----------------
__global__ void weighted_k(const float* __restrict__ poses, const float* __restrict__ att,
                           float* __restrict__ w34) {
    int t = blockIdx.x;
    int b = blockIdx.y;
    int f = threadIdx.x;
    if (f >= NF) return;
    const float* pb = poses + (long long)b * POSE_ROWS * NF + t * NF + f;
    const float* ab = att + b * VN;
    float acc = 0.f;
    for (int v = 0; v < VN; v++) acc += ab[v] * pb[v * NF];
    w34[(long long)b * DCTN * NF + t * NF + f] = acc;
}

// ---------------- x = concat(dct_in, dct_att); node-major f32 + feature-major bf16 ----
__global__ void build_x(const float* __restrict__ poses, const float* __restrict__ w34,
                        const float* __restrict__ dctm, float* __restrict__ x32,
                        ushort* __restrict__ xT16) {
    int idx = blockIdx.x * 256 + threadIdx.x;
    if (idx >= BATCH * NF * 68) return;
    int kk = idx % 68;
    int f = (idx / 68) % NF;
    int b = idx / (68 * NF);
    float acc = 0.f;
    if (kk < DCTN) {
        const float* pb = poses + (long long)b * POSE_ROWS * NF;
        #pragma unroll
        for (int t = 0; t < DCTN; t++) {
            int row = (t < KQ) ? (INN - KQ + t) : (INN - 1);
            acc += dctm[kk * DCTN + t] * pb[row * NF + f];
        }
    } else {
        int k2 = kk - DCTN;
        const float* wb = w34 + (long long)b * DCTN * NF + f;
        #pragma unroll
        for (int t = 0; t < DCTN; t++) acc += dctm[k2 * DCTN + t] * wb[t * NF];
    }
    long long R = (long long)b * NODEP + f;
    x32[R * 68 + kk] = acc;
    xT16[(long long)kk * RP + R] = f2bf(acc);
}

// ---------------- preds[b,t,f] = sum_k dct[k][10+t] * h32[(b*136+f)*68+k] ----------------
__global__ void idct_out(const float* __restrict__ h32, const float* __restrict__ dctm,
                         float* __restrict__ out) {
    int idx = blockIdx.x * 256 + threadIdx.x;
    if (idx >= BATCH * OUTN * NF) return;
    int f = idx % NF;
    int t = (idx / NF) % OUTN;
    int b = idx / (NF * OUTN);
    const float* yr = h32 + ((long long)b * NODEP + f) * 68;
    float acc = 0.f;
    #pragma unroll
    for (int k = 0; k < DCTN; k++) acc += dctm[k * DCTN + (KQ + t)] * yr[k];
    out[idx] = acc;
}

// ---------------- host ----------------
extern "C" void kernel_launch(void* const* d_in, const int* in_sizes, int n_in,
                              void* d_out, int out_size, void* d_ws, size_t ws_size,
                              hipStream_t stream) {
    const float* poses   = (const float*)d_in[0];
    const float* qw1     = (const float*)d_in[1];
    const float* qw2     = (const float*)d_in[2];
    const float* kw1     = (const float*)d_in[3];
    const float* kw2     = (const float*)d_in[4];
    const float* gc1_att = (const float*)d_in[5];
    const float* gc1_w   = (const float*)d_in[6];
    const float* gc1_b   = (const float*)d_in[7];
    const float* bn1_g   = (const float*)d_in[8];
    const float* bn1_b   = (const float*)d_in[9];
    const float* gcb_att = (const float*)d_in[10];
    const float* gcb_w   = (const float*)d_in[11];
    const float* gcb_b   = (const float*)d_in[12];
    const float* gcb_g   = (const float*)d_in[13];
    const float* gcb_beta= (const float*)d_in[14];
    const float* gc7_att = (const float*)d_in[15];
    const float* gc7_w   = (const float*)d_in[16];
    const float* gc7_b   = (const float*)d_in[17];
    float* out = (float*)d_out;
    float* w = (float*)d_ws;

    // ---- workspace layout (f32 units) ----
    float* dct   = w;                      // 1156 -> pad 1280
    float* att   = w + 1280;               // -> 23808
    float* w34   = w + 23808;              // -> 1198848
    float* x32   = w + 1198848;            // RP*68 -> 3566336
    float* h32   = w + 3566336;            // RP*68 -> 5933824
    float* qf    = w + 5933824;            // -> 6064896
    ushort* su   = (ushort*)(w + 6064896); // bf16 weight region
    ushort* WT1    = su;                   // 512*128   = 65536
    ushort* WTb    = su + 65536;           // 4*512*512 = 1048576
    ushort* WT7    = su + 1114112;         // 68*512    = 34816
    ushort* A16_1  = su + 1148928;         // 135*192   = 25920
    ushort* A16_B  = su + 1174848;         // 540*192   = 103680
    ushort* A16_7  = su + 1278528;         // 25920
    float* bnT   = w + 6717120;            // 10 * 69632 -> 7413440
    float* kf    = w + 7413440;            // 256*87*512 -> 18816704
    ushort* R2   = (ushort*)(w + 18816704);
    ushort* yT16  = R2;
    ushort* r1k16 = R2;                    // phase-A alias
    ushort* r1q16 = R2 + 11927552;
    ushort* R3   = (ushort*)(w + 27729600);
    ushort* hT16  = R3;
    ushort* pb16  = R3;                    // phase-A alias
    ushort* Wt1k  = R3 + 5013504;
    ushort* Wt1q  = R3 + 5439488;
    ushort* Wt2k  = R3 + 5865472;
    ushort* Wt2q  = R3 + 7176192;
    ushort* R4   = (ushort*)(w + 36642496);
    ushort* zN16  = R4;
    ushort* xT16  = R4;                    // alias (dead before zN16 written)
    ushort* z116  = R4 + 2367488;          // RP*80
    float* zpadf = w + 45555392;           // 128 f zero page
    const ushort* zpad = (const ushort*)zpadf;

    const int INF_RPB = 1 << 30;

    // allow 139 KB dynamic LDS for fused_layer (graph-safe: not a stream op)
    static int lds_set = 0;
    if (!lds_set) {
        hipFuncSetAttribute((const void*)fused_layer,
                            hipFuncAttributeMaxDynamicSharedMemorySize, 139264);
        lds_set = 1;
    }

    // ---- fused prep (one dispatch) ----
    prep_all<<<PB_DCT, 256, 0, stream>>>(
        poses, pb16, kw1, qw1, Wt1k, Wt1q, kw2, qw2, Wt2k, Wt2q,
        gc1_w, WT1, gcb_w, WTb, gc7_w, WT7,
        gc1_att, A16_1, gcb_att, A16_B, gc7_att, A16_7,
        bn1_g, bn1_b, gcb_g, gcb_beta, bnT, zpadf, dct);

    // ---- conv stack ----
    // conv1k: BM=128,BN=64; A-stream m-partitioned per XCD (mode 2): 182 m-blocks, Pc=23
    gemm2<128,64><<<dim3(1472, 1, 1), 256, 0, stream>>>(pb16, Wt1k, zpad, 23296, 512, 832,
        2, 8, 23, 91, 19584LL, 136LL, 0LL, 832LL, 0LL,
        (float*)nullptr, r1k16, 0LL, 512LL, 1LL, 1, nullptr, 0, nullptr, nullptr, 0, nullptr, nullptr);
    gemm2<128,128><<<dim3(4, 10, 1), 256, 0, stream>>>(pb16 + 110*136, Wt1q, zpad, 1280, 512, 832,
        0, 0, 0, 5, 19584LL, 136LL, 0LL, 832LL, 0LL,
        (float*)nullptr, r1q16, 0LL, 512LL, 1LL, 1, nullptr, 0, nullptr, nullptr, 0, nullptr, nullptr);
    // conv2k: BM=128,BN=64; mode 2: 174 m-blocks, Pc=22
    gemm2<128,64><<<dim3(1408, 1, 1), 256, 0, stream>>>(r1k16, Wt2k, zpad, 22272, 512, 2560,
        2, 8, 22, 87, 46592LL, 512LL, 0LL, 2560LL, 0LL,
        kf, (ushort*)nullptr, 0LL, 512LL, 1LL, 1, nullptr, 0, nullptr, nullptr, 0, nullptr, nullptr);
    gemm2<64,64><<<dim3(8, 4, 1), 256, 0, stream>>>(r1q16, Wt2q, zpad, 256, 512, 2560,
        0, 0, 0, INF_RPB, 0LL, 2560LL, 0LL, 2560LL, 0LL,
        qf, (ushort*)nullptr, 0LL, 512LL, 1LL, 1, nullptr, 0, nullptr, nullptr, 0, nullptr, nullptr);

    // ---- attention + x ----
    att_k<<<BATCH, 256, 0, stream>>>(kf, qf, att);
    weighted_k<<<dim3(DCTN, BATCH), 192, 0, stream>>>(poses, att, w34);
    build_x<<<(BATCH * NF * 68 + 255) / 256, 256, 0, stream>>>(poses, w34, dct, x32, xT16);

    // ---- gc1: mix then W(68->512) ----
    gemm2<64,64><<<dim3(3, 2, BATCH), 256, 0, stream>>>(xT16, A16_1, zpad, 68, 135, 192,
        0, 0, 0, INF_RPB, 0LL, (long long)RP, 136LL, 192LL, 0LL,
        (float*)nullptr, z116, 10880LL, 1LL, 80LL, 0, nullptr, 0, nullptr, nullptr, 0, nullptr, nullptr);
    // gc1 W: BM=128,BN=64; B-stream n-partitioned per XCD (mode 1): MBc=4, Pc=68
    gemm2<128,64><<<dim3(2176, 1, 1), 256, 0, stream>>>(WT1, z116, zpad, 512, RP, 128,
        1, 4, 68, INF_RPB, 0LL, 128LL, 0LL, 80LL, 0LL,
        (float*)nullptr, yT16, 0LL, (long long)RP, 1LL, 0, gc1_b, 1, bnT, bnT + 69632, 1, nullptr, nullptr);

    // ---- residual GCN blocks: one fused dispatch per layer ----
    for (int L = 0; L < 4; L++) {
        const ushort* min = (L & 1) ? hT16 : yT16;
        ushort* mout = (L & 1) ? yT16 : hT16;
        fused_layer<<<dim3(BATCH, 1, 1), 512, 139264, stream>>>(
            min, A16_B + L * 25920, WTb + L * 262144, zpad,
            gcb_b + L * 512, bnT + (1 + L) * 139264, bnT + (1 + L) * 139264 + 69632,
            (L & 1) ? yT16 : (const ushort*)nullptr, mout);
    }

    // ---- gc7: mix then W(512->68) + bias + x residual ----
    gemm2<64,64><<<dim3(3, 8, BATCH), 256, 0, stream>>>(yT16, A16_7, zpad, 512, 135, 192,
        0, 0, 0, INF_RPB, 0LL, (long long)RP, 136LL, 192LL, 0LL,
        (float*)nullptr, zN16, 69632LL, 1LL, 512LL, 0, nullptr, 0, nullptr, nullptr, 0, nullptr, nullptr);
    // gc7 W: BM=64,BN=64; A-stream m-partitioned per XCD (mode 2): NBc=2, Pc=68
    gemm2<64,64><<<dim3(1088, 1, 1), 256, 0, stream>>>(zN16, WT7, zpad, RP, 68, 512,
        2, 2, 68, INF_RPB, 0LL, 512LL, 0LL, 512LL, 0LL,
        h32, (ushort*)nullptr, 0LL, 68LL, 1LL, 0, gc7_b, 2, nullptr, nullptr, 0, nullptr, x32);

    idct_out<<<(BATCH * OUTN * NF + 255) / 256, 256, 0, stream>>>(h32, dct, out);
}